// Round 6
// baseline (514.850 us; speedup 1.0000x reference)
//
#include <hip/hip_runtime.h>

typedef short short8 __attribute__((ext_vector_type(8)));
typedef float f32x4 __attribute__((ext_vector_type(4)));

#define NK 512
#define SUBD 256
#define TT 2048
#define BD 512
#define NROWS 65536
#define DECAYF 0.99f
#define OMDF 0.01f
#define EPSF 1e-5f
#define FLT_BIG 3.402823466e+38f

static __device__ __forceinline__ ushort f2bf(float f) {
    uint u = __float_as_uint(f);
    u += 0x7FFFu + ((u >> 16) & 1u);
    return (ushort)(u >> 16);
}
static __device__ __forceinline__ float bf2f(ushort h) {
    return __uint_as_float(((uint)h) << 16);
}
union UCast { uint4 u; short8 s; };
static __device__ __forceinline__ short8 as_s8(uint4 v) { UCast c; c.u = v; return c.s; }

// async global->LDS, 16B per lane; LDS dest must be wave-uniform base (+lane*16)
static __device__ __forceinline__ void gload_lds16(const uint4* g, uint4* l) {
    __builtin_amdgcn_global_load_lds(
        (const __attribute__((address_space(1))) void*)g,
        (__attribute__((address_space(3))) void*)l, 16, 0, 0);
}

// ---------------- P0: sume2[h][k] = sum_c emb[k][c]^2 (exact fp32) ----------------
__global__ __launch_bounds__(256) void vq_sume2(const float* __restrict__ emb1,
                                                const float* __restrict__ emb2,
                                                float* __restrict__ sume2) {
    int r = blockIdx.x * 256 + threadIdx.x;
    const float* e = (r >> 9) ? emb2 : emb1;
    const float* row = e + (size_t)(r & 511) * SUBD;
    float s = 0.f;
#pragma unroll 8
    for (int i = 0; i < 64; ++i) {
        float4 v = *reinterpret_cast<const float4*>(row + i * 4);
        s += v.x * v.x + v.y * v.y + v.z * v.z + v.w * v.w;
    }
    sume2[r] = s;
}

// ---------------- P1: emb -> split-bf16, pre-swizzled staged layout ----------------
// embst[h][s=kh*8+cs][spl][k 0..255][pg 0..3]; phys pg holds logical group pg^((k>>1)&3)
__global__ __launch_bounds__(256) void vq_embcvt(const float* __restrict__ emb1,
                                                 const float* __restrict__ emb2,
                                                 uint4* __restrict__ embst) {
    int id = blockIdx.x * 256 + threadIdx.x;      // 0..65535
    int h   = id >> 15;
    int s   = (id >> 11) & 15;
    int spl = (id >> 10) & 1;
    int k   = (id >> 2) & 255;
    int gp  = id & 3;
    int kh = s >> 3, cs = s & 7;
    int gl = gp ^ ((k >> 1) & 3);                 // un-swizzle to logical c-group
    const float* e = h ? emb2 : emb1;
    const float* src = e + (size_t)(kh * 256 + k) * SUBD + cs * 32 + gl * 8;
    float4 v0 = *reinterpret_cast<const float4*>(src);
    float4 v1 = *reinterpret_cast<const float4*>(src + 4);
    float f[8] = {v0.x, v0.y, v0.z, v0.w, v1.x, v1.y, v1.z, v1.w};
    ushort o[8];
#pragma unroll
    for (int i = 0; i < 8; ++i) {
        ushort hh = f2bf(f[i]);
        o[i] = spl ? f2bf(f[i] - bf2f(hh)) : hh;
    }
    uint4 d;
    d.x = o[0] | ((uint)o[1] << 16);
    d.y = o[2] | ((uint)o[3] << 16);
    d.z = o[4] | ((uint)o[5] << 16);
    d.w = o[6] | ((uint)o[7] << 16);
    embst[id] = d;
}

// ---------------- X1: x -> transposed split-bf16 planes (argmin LDS order) + f2 ----
// plane[h][rblk][row 64][physchunk 32] (uint4); phys = chunk ^ (row&7)
__global__ __launch_bounds__(512) void vq_x1(const float* __restrict__ x,
                                             uint4* __restrict__ planeH,
                                             uint4* __restrict__ planeL,
                                             float* __restrict__ f2g) {
    __shared__ uint4 AhL[2048];
    __shared__ uint4 AlL[2048];
    __shared__ float f2p[512];
    const int tid = threadIdx.x;
    const int h  = blockIdx.x & 1;
    const int rb = blockIdx.x >> 1;
    const int b  = rb >> 5;
    const int t0 = (rb & 31) << 6;
    const int r  = tid & 63;
    const int co = (tid >> 6) * 32;
    const float* xb = x + ((size_t)b * BD + h * 256 + co) * TT + t0 + r;
    float f2 = 0.f;
#pragma unroll
    for (int j4 = 0; j4 < 4; ++j4) {
        float v[8];
#pragma unroll
        for (int j = 0; j < 8; ++j) v[j] = xb[(size_t)(j4 * 8 + j) * TT];
        ushort hi[8], lo[8];
#pragma unroll
        for (int j = 0; j < 8; ++j) {
            hi[j] = f2bf(v[j]);
            lo[j] = f2bf(v[j] - bf2f(hi[j]));
            f2 += v[j] * v[j];
        }
        uint4 uh, ul;
        uh.x = hi[0] | ((uint)hi[1] << 16); uh.y = hi[2] | ((uint)hi[3] << 16);
        uh.z = hi[4] | ((uint)hi[5] << 16); uh.w = hi[6] | ((uint)hi[7] << 16);
        ul.x = lo[0] | ((uint)lo[1] << 16); ul.y = lo[2] | ((uint)lo[3] << 16);
        ul.z = lo[4] | ((uint)lo[5] << 16); ul.w = lo[6] | ((uint)lo[7] << 16);
        const int chunk = (co >> 3) + j4;
        const int phys = chunk ^ (r & 7);
        AhL[r * 32 + phys] = uh;
        AlL[r * 32 + phys] = ul;
    }
    f2p[tid] = f2;
    __syncthreads();
    const size_t pb = (size_t)(h * 1024 + rb) * 2048;
#pragma unroll
    for (int i = 0; i < 4; ++i) {
        planeH[pb + tid + i * 512] = AhL[tid + i * 512];
        planeL[pb + tid + i * 512] = AlL[tid + i * 512];
    }
    if (tid < 64) {
        float s = 0.f;
#pragma unroll
        for (int g = 0; g < 8; ++g) s += f2p[g * 64 + tid];   // ascending c order
        f2g[h * NROWS + rb * 64 + tid] = s;
    }
}

// ---------------- A: argmin — A in LDS (DMA-staged), B streamed global->regs -------
// grid 2048 = (rblk,h); 512 thr = 8 waves (2 wr x 4 wk); wave tile 32r x 64k.
// No barriers in the K/C loop; 2 blocks/CU (LDS ~70 KB, VGPR capped 128).
__global__ __launch_bounds__(512, 4) void vq_argmin5(const uint4* __restrict__ planeH,
                                                     const uint4* __restrict__ planeL,
                                                     const uint4* __restrict__ embst,
                                                     const float* __restrict__ f2g,
                                                     const float* __restrict__ sume2,
                                                     float* __restrict__ counts,
                                                     int* __restrict__ idx_out) {
    __shared__ uint4 Ah[2048];        // 32 KB
    __shared__ uint4 Al[2048];        // 32 KB
    __shared__ float f2s[64];
    __shared__ float se_l[512];
    __shared__ float wbd[4][64];
    __shared__ int   wbk[4][64];

    const int tid = threadIdx.x;
    const int h  = blockIdx.x & 1;
    const int rb = blockIdx.x >> 1;
    const int wv = tid >> 6;
    const int lane = tid & 63;

    // ---- DMA prologue: A (hi+lo) ----
    {
        const size_t pb = (size_t)(h * 1024 + rb) * 2048;
        const uint4* sH = planeH + pb;
        const uint4* sL = planeL + pb;
#pragma unroll
        for (int i = 0; i < 4; ++i) {
            const int o = wv * 256 + i * 64;
            gload_lds16(sH + o + lane, &Ah[o]);
            gload_lds16(sL + o + lane, &Al[o]);
        }
    }
    se_l[tid] = sume2[h * NK + tid];
    if (tid < 64) f2s[tid] = f2g[h * NROWS + rb * 64 + tid];
    __syncthreads();      // A resident; the ONLY barrier before the epilogue

    const int l15 = lane & 15, l4 = lane >> 4;
    const int wr = wv >> 2, wk = wv & 3;
    const uint4* eb = embst + (size_t)h * 32768;
    const int bLane = wk * 256 + l15 * 4 + (l4 ^ ((l15 >> 1) & 3));

    float bd8[8]; int bk8[8];
#pragma unroll
    for (int i = 0; i < 8; ++i) { bd8[i] = FLT_BIG; bk8[i] = 0; }

#pragma unroll
    for (int kh = 0; kh < 2; ++kh) {
        f32x4 acc[2][4];
#pragma unroll
        for (int rg = 0; rg < 2; ++rg)
#pragma unroll
            for (int kg = 0; kg < 4; ++kg) acc[rg][kg] = (f32x4)0.f;

        uint4 bh[2][4], bl[4];
        // preload hi fragments for stage kh*8
#pragma unroll
        for (int kg = 0; kg < 4; ++kg) bh[0][kg] = eb[(size_t)(kh * 8) * 2048 + bLane + kg * 64];

#pragma unroll
        for (int cs = 0; cs < 8; ++cs) {
            const int s = kh * 8 + cs;
            const int cur = cs & 1, nxt = cur ^ 1;
            // issue lo loads for current stage (consumed after the ah*bh block)
#pragma unroll
            for (int kg = 0; kg < 4; ++kg)
                bl[kg] = eb[(size_t)s * 2048 + 1024 + bLane + kg * 64];
            // issue hi loads for next stage (reg double-buffer)
            const int sn = (s < 15) ? s + 1 : 15;
#pragma unroll
            for (int kg = 0; kg < 4; ++kg)
                bh[nxt][kg] = eb[(size_t)sn * 2048 + bLane + kg * 64];
            // A fragments from LDS (conflict-free swizzle)
            short8 ah[2], al[2];
#pragma unroll
            for (int rg = 0; rg < 2; ++rg) {
                const int row = wr * 32 + rg * 16 + l15;
                const int ia = row * 32 + ((cs * 4 + l4) ^ (row & 7));
                ah[rg] = as_s8(Ah[ia]);
                al[rg] = as_s8(Al[ia]);
            }
            // hi*hi first (bh[cur] ready from previous stage)
#pragma unroll
            for (int rg = 0; rg < 2; ++rg)
#pragma unroll
                for (int kg = 0; kg < 4; ++kg)
                    acc[rg][kg] = __builtin_amdgcn_mfma_f32_16x16x32_bf16(ah[rg], as_s8(bh[cur][kg]), acc[rg][kg], 0, 0, 0);
            // hi*lo (bl had ~8 MFMAs of latency cover)
#pragma unroll
            for (int rg = 0; rg < 2; ++rg)
#pragma unroll
                for (int kg = 0; kg < 4; ++kg)
                    acc[rg][kg] = __builtin_amdgcn_mfma_f32_16x16x32_bf16(ah[rg], as_s8(bl[kg]), acc[rg][kg], 0, 0, 0);
            // lo*hi
#pragma unroll
            for (int rg = 0; rg < 2; ++rg)
#pragma unroll
                for (int kg = 0; kg < 4; ++kg)
                    acc[rg][kg] = __builtin_amdgcn_mfma_f32_16x16x32_bf16(al[rg], as_s8(bh[cur][kg]), acc[rg][kg], 0, 0, 0);
        }
        // ---- lane-local argmin update (k ascending -> strict < = min-k tie-break) ----
#pragma unroll
        for (int rg = 0; rg < 2; ++rg)
#pragma unroll
            for (int kg = 0; kg < 4; ++kg) {
                const int k = kh * 256 + wk * 64 + kg * 16 + l15;
                const float se = se_l[k];
#pragma unroll
                for (int reg = 0; reg < 4; ++reg) {
                    const int row = wr * 32 + rg * 16 + l4 * 4 + reg;
                    const float d = (f2s[row] + se) - 2.0f * acc[rg][kg][reg];
                    const int i8 = rg * 4 + reg;
                    if (d < bd8[i8]) { bd8[i8] = d; bk8[i8] = k; }
                }
            }
    }

#pragma unroll
    for (int m = 1; m < 16; m <<= 1) {
#pragma unroll
        for (int i = 0; i < 8; ++i) {
            const float od = __shfl_xor(bd8[i], m);
            const int   ok = __shfl_xor(bk8[i], m);
            if (od < bd8[i] || (od == bd8[i] && ok < bk8[i])) { bd8[i] = od; bk8[i] = ok; }
        }
    }
    if (l15 == 0) {
#pragma unroll
        for (int i = 0; i < 8; ++i) {
            const int rg = i >> 2, reg = i & 3;
            const int rr = wr * 32 + rg * 16 + l4 * 4 + reg;
            wbd[wk][rr] = bd8[i]; wbk[wk][rr] = bk8[i];
        }
    }
    __syncthreads();
    if (tid < 64) {
        float bd = wbd[0][tid]; int bk = wbk[0][tid];
#pragma unroll
        for (int q = 1; q < 4; ++q) {
            const float od = wbd[q][tid]; const int ok = wbk[q][tid];
            if (od < bd || (od == bd && ok < bk)) { bd = od; bk = ok; }
        }
        idx_out[h * NROWS + rb * 64 + tid] = bk;
        atomicAdd(&counts[(h << 9) + bk], 1.0f);
    }
}

// ---------------- B: cluster-major segmented sum from planes -> new_emb ------------
__global__ __launch_bounds__(256) void vq_dwseg2(const uint4* __restrict__ planeH,
                                                 const uint4* __restrict__ planeL,
                                                 const int* __restrict__ idx,
                                                 const float* __restrict__ w1,
                                                 const float* __restrict__ w2,
                                                 const float* __restrict__ csf,
                                                 float* __restrict__ nemb) {
    __shared__ ushort rows_l[4][1024];
    __shared__ int cnt_w[4];
    const int tid = threadIdx.x;
    const int h = blockIdx.x >> 9;
    const int k = blockIdx.x & 511;
    const int w = tid >> 6, lane = tid & 63;
    const ushort* pH = (const ushort*)planeH;
    const ushort* pL = (const ushort*)planeL;
    const int c = tid;
    const size_t hbase = (size_t)h * 1024 * 16384;    // ushorts per half
    float acc = 0.f;
    for (int win = 0; win < 4; ++win) {
        {
            const int base = win * 16384 + w * 4096;
            const int* ip = idx + h * NROWS + base;
            int cnt = 0;
            for (int stp = 0; stp < 64; ++stp) {
                const int rl = stp * 64 + lane;
                const bool mt = (ip[rl] == k);
                const unsigned long long m = __ballot(mt);
                if (mt) {
                    const int pos = cnt + __popcll(m & ((1ull << lane) - 1ull));
                    if (pos < 1024) rows_l[w][pos] = (ushort)rl;
                }
                cnt += __popcll(m);
            }
            if (lane == 0) cnt_w[w] = (cnt < 1024) ? cnt : 1024;
        }
        __syncthreads();
        for (int s = 0; s < 4; ++s) {
            const int n = cnt_w[s];
            const int rbase = win * 16384 + s * 4096;
            for (int i = 0; i < n; ++i) {
                const int r = rbase + rows_l[s][i];
                const size_t off = hbase + (size_t)(r >> 6) * 16384 + (r & 63) * 256
                                 + (((c >> 3) ^ (r & 7)) << 3) + (c & 7);
                acc += bf2f(pH[off]) + bf2f(pL[off]);
            }
        }
        __syncthreads();
    }
    const float* wsrc = h ? w2 : w1;
    nemb[((size_t)(h << 9) + k) * SUBD + c] =
        (DECAYF * wsrc[(size_t)k * SUBD + c] + OMDF * acc) / csf[(h << 9) + k];
}

// ---------------- D1: EMA cluster-size smoothing + perplexity ----------------
__global__ void vq_stats(const float* __restrict__ counts,
                         const float* __restrict__ cs_in1,
                         const float* __restrict__ cs_in2,
                         float* __restrict__ cs_final,
                         float* __restrict__ out) {
    __shared__ float red[512];
    const int k = threadIdx.x;
    float perp_tot = 0.f;
    for (int h = 0; h < 2; ++h) {
        const float* csin = h ? cs_in2 : cs_in1;
        float cnt = counts[(h << 9) + k];
        float csn = DECAYF * csin[k] + OMDF * cnt;
        red[k] = csn;
        __syncthreads();
        for (int s = 256; s > 0; s >>= 1) {
            if (k < s) red[k] += red[k + s];
            __syncthreads();
        }
        float n = red[0];
        __syncthreads();
        cs_final[(h << 9) + k] = (csn + EPSF) / (n + 512.0f * EPSF) * n;
        float p = cnt * (1.0f / 65536.0f);
        float e = p * logf(p + 1e-10f);
        red[k] = e;
        __syncthreads();
        for (int s = 256; s > 0; s >>= 1) {
            if (k < s) red[k] += red[k + s];
            __syncthreads();
        }
        if (k == 0) perp_tot += expf(-red[0]);
        __syncthreads();
    }
    if (k == 0) out[33554433] = perp_tot;
}

// ---------------- fallback chain (ws too small for planes) ----------------
__global__ __launch_bounds__(512) void vq_argmin3(const float* __restrict__ x,
                                                  const uint4* __restrict__ embst,
                                                  const float* __restrict__ sume2,
                                                  float* __restrict__ counts,
                                                  int* __restrict__ idx_out) {
    __shared__ uint4 Ah[2048];
    __shared__ uint4 Al[2048];
    __shared__ uint4 Bb[2][2048];
    __shared__ float f2s[64];
    __shared__ float se_l[512];
    __shared__ float wbd[4][64];
    __shared__ int   wbk[4][64];
    const int tid = threadIdx.x;
    const int h  = blockIdx.x & 1;
    const int rb = blockIdx.x >> 1;
    const int b  = rb >> 5;
    const int t0 = (rb & 31) << 6;
    if (tid < 64) f2s[tid] = 0.f;
    se_l[tid] = sume2[h * NK + tid];
    __syncthreads();
    {
        const int r  = tid & 63;
        const int cq = tid >> 6;
        const float* xb = x + ((size_t)b * BD + h * 256) * TT + t0 + r;
        float f2p = 0.f;
#pragma unroll
        for (int it = 0; it < 4; ++it) {
            const int c0 = cq * 32 + it * 8;
            float v[8];
#pragma unroll
            for (int j = 0; j < 8; ++j) v[j] = xb[(size_t)(c0 + j) * TT];
            ushort hi[8], lo[8];
#pragma unroll
            for (int j = 0; j < 8; ++j) {
                hi[j] = f2bf(v[j]);
                lo[j] = f2bf(v[j] - bf2f(hi[j]));
                f2p += v[j] * v[j];
            }
            uint4 uh, ul;
            uh.x = hi[0] | ((uint)hi[1] << 16); uh.y = hi[2] | ((uint)hi[3] << 16);
            uh.z = hi[4] | ((uint)hi[5] << 16); uh.w = hi[6] | ((uint)hi[7] << 16);
            ul.x = lo[0] | ((uint)lo[1] << 16); ul.y = lo[2] | ((uint)lo[3] << 16);
            ul.z = lo[4] | ((uint)lo[5] << 16); ul.w = lo[6] | ((uint)lo[7] << 16);
            const int phys = (c0 >> 3) ^ (r & 7);
            Ah[r * 32 + phys] = uh;
            Al[r * 32 + phys] = ul;
        }
        atomicAdd(&f2s[r], f2p);
    }
    {
        const uint4* src = embst + (size_t)h * 32768;
#pragma unroll
        for (int i = 0; i < 4; ++i) Bb[0][tid + i * 512] = src[tid + i * 512];
    }
    __syncthreads();
    const int l = tid & 63;
    const int wv = tid >> 6;
    const int wr = wv >> 2, wk = wv & 3;
    const int l15 = l & 15, l4 = l >> 4;
    const int bBase = l15 * 4 + (l4 ^ ((l15 >> 1) & 3));
    float bd8[8]; int bk8[8];
#pragma unroll
    for (int i = 0; i < 8; ++i) { bd8[i] = FLT_BIG; bk8[i] = 0; }
    int buf = 0;
    for (int kh = 0; kh < 2; ++kh) {
        f32x4 acc[2][4];
#pragma unroll
        for (int rg = 0; rg < 2; ++rg)
#pragma unroll
            for (int kg = 0; kg < 4; ++kg) acc[rg][kg] = (f32x4)0.f;
        for (int cs = 0; cs < 8; ++cs) {
            const int s = kh * 8 + cs;
            uint4 st[4];
            const bool pf = (s < 15);
            if (pf) {
                const uint4* src = embst + (size_t)h * 32768 + (size_t)(s + 1) * 2048;
#pragma unroll
                for (int i = 0; i < 4; ++i) st[i] = src[tid + i * 512];
            }
            short8 ah[2], al[2];
#pragma unroll
            for (int rg = 0; rg < 2; ++rg) {
                const int row = wr * 32 + rg * 16 + l15;
                const int ia = row * 32 + ((cs * 4 + l4) ^ (row & 7));
                ah[rg] = as_s8(Ah[ia]);
                al[rg] = as_s8(Al[ia]);
            }
            short8 bh[4], bl[4];
#pragma unroll
            for (int kg = 0; kg < 4; ++kg) {
                const int ib = wk * 256 + kg * 64 + bBase;
                bh[kg] = as_s8(Bb[buf][ib]);
                bl[kg] = as_s8(Bb[buf][1024 + ib]);
            }
#pragma unroll
            for (int rg = 0; rg < 2; ++rg)
#pragma unroll
                for (int kg = 0; kg < 4; ++kg) {
                    acc[rg][kg] = __builtin_amdgcn_mfma_f32_16x16x32_bf16(ah[rg], bh[kg], acc[rg][kg], 0, 0, 0);
                    acc[rg][kg] = __builtin_amdgcn_mfma_f32_16x16x32_bf16(ah[rg], bl[kg], acc[rg][kg], 0, 0, 0);
                    acc[rg][kg] = __builtin_amdgcn_mfma_f32_16x16x32_bf16(al[rg], bh[kg], acc[rg][kg], 0, 0, 0);
                }
            if (pf) {
#pragma unroll
                for (int i = 0; i < 4; ++i) Bb[buf ^ 1][tid + i * 512] = st[i];
            }
            __syncthreads();
            buf ^= 1;
        }
#pragma unroll
        for (int rg = 0; rg < 2; ++rg)
#pragma unroll
            for (int kg = 0; kg < 4; ++kg) {
                const int k = kh * 256 + wk * 64 + kg * 16 + l15;
                const float se = se_l[k];
#pragma unroll
                for (int reg = 0; reg < 4; ++reg) {
                    const int row = wr * 32 + rg * 16 + l4 * 4 + reg;
                    const float d = (f2s[row] + se) - 2.0f * acc[rg][kg][reg];
                    const int i8 = rg * 4 + reg;
                    if (d < bd8[i8]) { bd8[i8] = d; bk8[i8] = k; }
                }
            }
    }
#pragma unroll
    for (int m = 1; m < 16; m <<= 1) {
#pragma unroll
        for (int i = 0; i < 8; ++i) {
            const float od = __shfl_xor(bd8[i], m);
            const int   ok = __shfl_xor(bk8[i], m);
            if (od < bd8[i] || (od == bd8[i] && ok < bk8[i])) { bd8[i] = od; bk8[i] = ok; }
        }
    }
    if (l15 == 0) {
#pragma unroll
        for (int i = 0; i < 8; ++i) {
            const int rg = i >> 2, reg = i & 3;
            const int rr = wr * 32 + rg * 16 + l4 * 4 + reg;
            wbd[wk][rr] = bd8[i]; wbk[wk][rr] = bk8[i];
        }
    }
    __syncthreads();
    if (tid < 64) {
        float bd = wbd[0][tid]; int bk = wbk[0][tid];
#pragma unroll
        for (int q = 1; q < 4; ++q) {
            const float od = wbd[q][tid]; const int ok = wbk[q][tid];
            if (od < bd || (od == bd && ok < bk)) { bd = od; bk = ok; }
        }
        idx_out[h * NROWS + b * TT + t0 + tid] = bk;
        atomicAdd(&counts[(h << 9) + bk], 1.0f);
    }
}

__global__ __launch_bounds__(256) void vq_dw(const float* __restrict__ x,
                                             const int* __restrict__ idx,
                                             float* __restrict__ dw) {
    __shared__ float dwp[64 * 512];
    const int tid = threadIdx.x;
    const int h = blockIdx.x & 1;
    const int cr = (blockIdx.x >> 1) & 3;
    const int slab = blockIdx.x >> 3;
#pragma unroll 8
    for (int i = 0; i < 128; ++i) dwp[tid + i * 256] = 0.f;
    __syncthreads();
    for (int it = 0; it < 16; ++it) {
        const int r = (slab << 12) + (it << 8) + tid;
        const int k = idx[(h << 16) + r];
        const float* xb = x + ((size_t)(r >> 11) * BD + (h << 8) + (cr << 6)) * TT + (r & 2047);
#pragma unroll
        for (int c = 0; c < 64; ++c)
            atomicAdd(&dwp[(c << 9) + k], xb[(size_t)c * TT]);
    }
    __syncthreads();
#pragma unroll 8
    for (int i = 0; i < 128; ++i) {
        const int j = tid + i * 256;
        atomicAdd(&dw[(size_t)((h << 9) + (j & 511)) * SUBD + (cr << 6) + (j >> 9)], dwp[j]);
    }
}

__global__ __launch_bounds__(256) void vq_newemb(const float* __restrict__ dw,
                                                 const float* __restrict__ w1,
                                                 const float* __restrict__ w2,
                                                 const float* __restrict__ cs_final,
                                                 float* __restrict__ new_emb) {
    int g = blockIdx.x * 256 + threadIdx.x;
    int h = g >> 15;
    int k = (g >> 6) & 511;
    const float* wi = h ? w2 : w1;
    float4 d4 = *reinterpret_cast<const float4*>(dw + (size_t)g * 4);
    float4 w4 = *reinterpret_cast<const float4*>(wi + (size_t)(g & 32767) * 4);
    float cs = cs_final[(h << 9) + k];
    float4 o;
    o.x = (DECAYF * w4.x + OMDF * d4.x) / cs;
    o.y = (DECAYF * w4.y + OMDF * d4.y) / cs;
    o.z = (DECAYF * w4.z + OMDF * d4.z) / cs;
    o.w = (DECAYF * w4.w + OMDF * d4.w) / cs;
    *reinterpret_cast<float4*>(new_emb + (size_t)g * 4) = o;
}

// ---------------- E: gather + output + vq_loss ----------------
__global__ __launch_bounds__(256) void vq_out(const float* __restrict__ x,
                                              const float* __restrict__ nemb,
                                              const int* __restrict__ idx,
                                              float* __restrict__ out) {
    __shared__ int idx_l[2][64];
    __shared__ float wsum[4];
    const int tid = threadIdx.x;
    const int b = blockIdx.x >> 5;
    const int t0 = (blockIdx.x & 31) << 6;
    if (tid < 128) {
        int hh = tid >> 6, t = tid & 63;
        idx_l[hh][t] = idx[hh * NROWS + b * TT + t0 + t];
    }
    __syncthreads();
    const int tq = tid & 15;
    const int cw = tid >> 4;
    const int k0 = idx_l[0][tq * 4 + 0], k1 = idx_l[0][tq * 4 + 1];
    const int k2 = idx_l[0][tq * 4 + 2], k3 = idx_l[0][tq * 4 + 3];
    const int m0 = idx_l[1][tq * 4 + 0], m1 = idx_l[1][tq * 4 + 1];
    const int m2 = idx_l[1][tq * 4 + 2], m3 = idx_l[1][tq * 4 + 3];
    float lsum = 0.f;
    for (int i = 0; i < 32; ++i) {
        const int c = cw + i * 16;
        const int hh = c >> 8, cp = c & 255;
        const size_t base = ((size_t)b * BD + c) * TT + t0 + tq * 4;
        float4 xv = *reinterpret_cast<const float4*>(x + base);
        const size_t eb = (size_t)(hh << 9) * SUBD + cp;
        float q0 = nemb[eb + (size_t)(hh ? m0 : k0) * SUBD];
        float q1 = nemb[eb + (size_t)(hh ? m1 : k1) * SUBD];
        float q2 = nemb[eb + (size_t)(hh ? m2 : k2) * SUBD];
        float q3 = nemb[eb + (size_t)(hh ? m3 : k3) * SUBD];
        float4 o; float t1;
        t1 = q0 - xv.x; o.x = xv.x + t1; lsum += t1 * t1;
        t1 = q1 - xv.y; o.y = xv.y + t1; lsum += t1 * t1;
        t1 = q2 - xv.z; o.z = xv.z + t1; lsum += t1 * t1;
        t1 = q3 - xv.w; o.w = xv.w + t1; lsum += t1 * t1;
        *reinterpret_cast<float4*>(out + base) = o;
    }
#pragma unroll
    for (int m = 1; m < 64; m <<= 1) lsum += __shfl_xor(lsum, m);
    if ((tid & 63) == 0) wsum[tid >> 6] = lsum;
    __syncthreads();
    if (tid == 0) {
        float s = wsum[0] + wsum[1] + wsum[2] + wsum[3];
        atomicAdd(out + 33554432, s * (0.25f / 33554432.0f));
    }
}

extern "C" void kernel_launch(void* const* d_in, const int* in_sizes, int n_in,
                              void* d_out, int out_size, void* d_ws, size_t ws_size,
                              hipStream_t stream) {
    const float* x    = (const float*)d_in[0];
    const float* emb1 = (const float*)d_in[1];
    const float* emb2 = (const float*)d_in[2];
    const float* cs1  = (const float*)d_in[3];
    const float* w1   = (const float*)d_in[4];
    const float* cs2  = (const float*)d_in[5];
    const float* w2   = (const float*)d_in[6];
    float* out = (float*)d_out;
    float* ws  = (float*)d_ws;

    float* counts = ws;                     // 1024
    float* csf    = ws + 1024;              // 1024
    float* se2    = ws + 2048;              // 1024
    float* nemb   = ws + 3072;              // 262144
    int*   idx    = (int*)(ws + 265216);    // 131072 ints
    uint4* embst  = (uint4*)(ws + 396288);  // 65536 uint4 (1 MB)
    float* f2g    = ws + 658432;            // 131072
    uint4* planeH = (uint4*)(ws + 789504);  // 4M uint4 (64 MB)
    uint4* planeL = (uint4*)(ws + 17566720);// 4M uint4 (64 MB)
    float* dw     = ws + 789504;            // fallback only (overlaps planeH)

    const size_t NEED = (size_t)(789504 + 2 * 16777216) * 4;
    const bool fast = (ws_size >= NEED);

    hipMemsetAsync(counts, 0, 1024 * sizeof(float), stream);
    hipMemsetAsync(out + 33554432, 0, 2 * sizeof(float), stream);

    vq_sume2 <<<4,   256, 0, stream>>>(emb1, emb2, se2);
    vq_embcvt<<<256, 256, 0, stream>>>(emb1, emb2, embst);

    if (fast) {
        vq_x1     <<<2048, 512, 0, stream>>>(x, planeH, planeL, f2g);
        vq_argmin5<<<2048, 512, 0, stream>>>(planeH, planeL, embst, f2g, se2, counts, idx);
        vq_stats  <<<1,    512, 0, stream>>>(counts, cs1, cs2, csf, out);
        vq_dwseg2 <<<1024, 256, 0, stream>>>(planeH, planeL, idx, w1, w2, csf, nemb);
    } else {
        hipMemsetAsync(dw, 0, 262144 * sizeof(float), stream);
        vq_argmin3<<<2048, 512, 0, stream>>>(x, embst, se2, counts, idx);
        vq_dw     <<<128,  256, 0, stream>>>(x, idx, dw);
        vq_stats  <<<1,    512, 0, stream>>>(counts, cs1, cs2, csf, out);
        vq_newemb <<<256,  256, 0, stream>>>(dw, w1, w2, csf, nemb);
    }
    vq_out<<<1024, 256, 0, stream>>>(x, nemb, idx, out);
}

// Round 7
// 360.528 us; speedup vs baseline: 1.4280x; 1.4280x over previous
//
#include <hip/hip_runtime.h>

typedef short short8 __attribute__((ext_vector_type(8)));
typedef float f32x4 __attribute__((ext_vector_type(4)));

#define NK 512
#define SUBD 256
#define TT 2048
#define BD 512
#define NROWS 65536
#define DECAYF 0.99f
#define OMDF 0.01f
#define EPSF 1e-5f
#define FLT_BIG 3.402823466e+38f

static __device__ __forceinline__ ushort f2bf(float f) {
    uint u = __float_as_uint(f);
    u += 0x7FFFu + ((u >> 16) & 1u);
    return (ushort)(u >> 16);
}
static __device__ __forceinline__ float bf2f(ushort h) {
    return __uint_as_float(((uint)h) << 16);
}
union UCast { uint4 u; short8 s; };
static __device__ __forceinline__ short8 as_s8(uint4 v) { UCast c; c.u = v; return c.s; }

// async global->LDS, 16B per lane; LDS dest must be wave-uniform base (+lane*16)
static __device__ __forceinline__ void gload_lds16(const uint4* g, uint4* l) {
    __builtin_amdgcn_global_load_lds(
        (const __attribute__((address_space(1))) void*)g,
        (__attribute__((address_space(3))) void*)l, 16, 0, 0);
}

// ---------------- P0: sume2[h][k] = sum_c emb[k][c]^2 (exact fp32) ----------------
__global__ __launch_bounds__(256) void vq_sume2(const float* __restrict__ emb1,
                                                const float* __restrict__ emb2,
                                                float* __restrict__ sume2) {
    int r = blockIdx.x * 256 + threadIdx.x;
    const float* e = (r >> 9) ? emb2 : emb1;
    const float* row = e + (size_t)(r & 511) * SUBD;
    float s = 0.f;
#pragma unroll 8
    for (int i = 0; i < 64; ++i) {
        float4 v = *reinterpret_cast<const float4*>(row + i * 4);
        s += v.x * v.x + v.y * v.y + v.z * v.z + v.w * v.w;
    }
    sume2[r] = s;
}

// ---------------- P1: emb -> split-bf16, pre-swizzled staged layout ----------------
// embst[h][s=kh*8+cs][spl][k 0..255][pg 0..3]; phys pg holds logical group pg^((k>>1)&3)
__global__ __launch_bounds__(256) void vq_embcvt(const float* __restrict__ emb1,
                                                 const float* __restrict__ emb2,
                                                 uint4* __restrict__ embst) {
    int id = blockIdx.x * 256 + threadIdx.x;      // 0..65535
    int h   = id >> 15;
    int s   = (id >> 11) & 15;
    int spl = (id >> 10) & 1;
    int k   = (id >> 2) & 255;
    int gp  = id & 3;
    int kh = s >> 3, cs = s & 7;
    int gl = gp ^ ((k >> 1) & 3);                 // un-swizzle to logical c-group
    const float* e = h ? emb2 : emb1;
    const float* src = e + (size_t)(kh * 256 + k) * SUBD + cs * 32 + gl * 8;
    float4 v0 = *reinterpret_cast<const float4*>(src);
    float4 v1 = *reinterpret_cast<const float4*>(src + 4);
    float f[8] = {v0.x, v0.y, v0.z, v0.w, v1.x, v1.y, v1.z, v1.w};
    ushort o[8];
#pragma unroll
    for (int i = 0; i < 8; ++i) {
        ushort hh = f2bf(f[i]);
        o[i] = spl ? f2bf(f[i] - bf2f(hh)) : hh;
    }
    uint4 d;
    d.x = o[0] | ((uint)o[1] << 16);
    d.y = o[2] | ((uint)o[3] << 16);
    d.z = o[4] | ((uint)o[5] << 16);
    d.w = o[6] | ((uint)o[7] << 16);
    embst[id] = d;
}

// ---------------- X1: x -> transposed split-bf16 planes (argmin LDS order) + f2 ----
// plane[h][rblk][row 64][physchunk 32] (uint4); phys = chunk ^ (row&7)
__global__ __launch_bounds__(512) void vq_x1(const float* __restrict__ x,
                                             uint4* __restrict__ planeH,
                                             uint4* __restrict__ planeL,
                                             float* __restrict__ f2g) {
    __shared__ uint4 AhL[2048];
    __shared__ uint4 AlL[2048];
    __shared__ float f2p[512];
    const int tid = threadIdx.x;
    const int h  = blockIdx.x & 1;
    const int rb = blockIdx.x >> 1;
    const int b  = rb >> 5;
    const int t0 = (rb & 31) << 6;
    const int r  = tid & 63;
    const int co = (tid >> 6) * 32;
    const float* xb = x + ((size_t)b * BD + h * 256 + co) * TT + t0 + r;
    float f2 = 0.f;
#pragma unroll
    for (int j4 = 0; j4 < 4; ++j4) {
        float v[8];
#pragma unroll
        for (int j = 0; j < 8; ++j) v[j] = xb[(size_t)(j4 * 8 + j) * TT];
        ushort hi[8], lo[8];
#pragma unroll
        for (int j = 0; j < 8; ++j) {
            hi[j] = f2bf(v[j]);
            lo[j] = f2bf(v[j] - bf2f(hi[j]));
            f2 += v[j] * v[j];
        }
        uint4 uh, ul;
        uh.x = hi[0] | ((uint)hi[1] << 16); uh.y = hi[2] | ((uint)hi[3] << 16);
        uh.z = hi[4] | ((uint)hi[5] << 16); uh.w = hi[6] | ((uint)hi[7] << 16);
        ul.x = lo[0] | ((uint)lo[1] << 16); ul.y = lo[2] | ((uint)lo[3] << 16);
        ul.z = lo[4] | ((uint)lo[5] << 16); ul.w = lo[6] | ((uint)lo[7] << 16);
        const int chunk = (co >> 3) + j4;
        const int phys = chunk ^ (r & 7);
        AhL[r * 32 + phys] = uh;
        AlL[r * 32 + phys] = ul;
    }
    f2p[tid] = f2;
    __syncthreads();
    const size_t pb = (size_t)(h * 1024 + rb) * 2048;
#pragma unroll
    for (int i = 0; i < 4; ++i) {
        planeH[pb + tid + i * 512] = AhL[tid + i * 512];
        planeL[pb + tid + i * 512] = AlL[tid + i * 512];
    }
    if (tid < 64) {
        float s = 0.f;
#pragma unroll
        for (int g = 0; g < 8; ++g) s += f2p[g * 64 + tid];   // ascending c order
        f2g[h * NROWS + rb * 64 + tid] = s;
    }
}

// ---------------- A: argmin — A in LDS (DMA-staged), B streamed global->regs -------
// grid 2048 = (rblk,h); 512 thr = 8 waves (2 wr x 4 wk); wave tile 32r x 64k.
// No barriers in the K/C loop; single-buffered B regs (live set <=128 incl AGPR).
__global__ __launch_bounds__(512, 2) void vq_argmin5(const uint4* __restrict__ planeH,
                                                     const uint4* __restrict__ planeL,
                                                     const uint4* __restrict__ embst,
                                                     const float* __restrict__ f2g,
                                                     const float* __restrict__ sume2,
                                                     float* __restrict__ counts,
                                                     int* __restrict__ idx_out) {
    __shared__ uint4 Ah[2048];        // 32 KB
    __shared__ uint4 Al[2048];        // 32 KB
    __shared__ float f2s[64];
    __shared__ float se_l[512];
    __shared__ float wbd[4][64];
    __shared__ int   wbk[4][64];

    const int tid = threadIdx.x;
    const int h  = blockIdx.x & 1;
    const int rb = blockIdx.x >> 1;
    const int wv = tid >> 6;
    const int lane = tid & 63;

    // ---- DMA prologue: A (hi+lo) ----
    {
        const size_t pb = (size_t)(h * 1024 + rb) * 2048;
        const uint4* sH = planeH + pb;
        const uint4* sL = planeL + pb;
#pragma unroll
        for (int i = 0; i < 4; ++i) {
            const int o = wv * 256 + i * 64;
            gload_lds16(sH + o + lane, &Ah[o]);
            gload_lds16(sL + o + lane, &Al[o]);
        }
    }
    se_l[tid] = sume2[h * NK + tid];
    if (tid < 64) f2s[tid] = f2g[h * NROWS + rb * 64 + tid];
    __syncthreads();      // A resident; the ONLY barrier before the epilogue

    const int l15 = lane & 15, l4 = lane >> 4;
    const int wr = wv >> 2, wk = wv & 3;
    const uint4* eb = embst + (size_t)h * 32768;
    const int bLane = wk * 256 + l15 * 4 + (l4 ^ ((l15 >> 1) & 3));

    float bd8[8]; int bk8[8];
#pragma unroll
    for (int i = 0; i < 8; ++i) { bd8[i] = FLT_BIG; bk8[i] = 0; }

#pragma unroll 1
    for (int kh = 0; kh < 2; ++kh) {
        f32x4 acc[2][4];
#pragma unroll
        for (int rg = 0; rg < 2; ++rg)
#pragma unroll
            for (int kg = 0; kg < 4; ++kg) acc[rg][kg] = (f32x4)0.f;

#pragma unroll 1
        for (int cs = 0; cs < 8; ++cs) {
            const int s = kh * 8 + cs;
            uint4 bh[4], bl[4];
            // issue all 8 B loads up front (independent, L2-resident)
#pragma unroll
            for (int kg = 0; kg < 4; ++kg)
                bh[kg] = eb[(size_t)s * 2048 + bLane + kg * 64];
#pragma unroll
            for (int kg = 0; kg < 4; ++kg)
                bl[kg] = eb[(size_t)s * 2048 + 1024 + bLane + kg * 64];
            // A fragments from LDS (conflict-free swizzle)
            short8 ah[2], al[2];
#pragma unroll
            for (int rg = 0; rg < 2; ++rg) {
                const int row = wr * 32 + rg * 16 + l15;
                const int ia = row * 32 + ((cs * 4 + l4) ^ (row & 7));
                ah[rg] = as_s8(Ah[ia]);
                al[rg] = as_s8(Al[ia]);
            }
            // hi*hi
#pragma unroll
            for (int rg = 0; rg < 2; ++rg)
#pragma unroll
                for (int kg = 0; kg < 4; ++kg)
                    acc[rg][kg] = __builtin_amdgcn_mfma_f32_16x16x32_bf16(ah[rg], as_s8(bh[kg]), acc[rg][kg], 0, 0, 0);
            // hi*lo
#pragma unroll
            for (int rg = 0; rg < 2; ++rg)
#pragma unroll
                for (int kg = 0; kg < 4; ++kg)
                    acc[rg][kg] = __builtin_amdgcn_mfma_f32_16x16x32_bf16(ah[rg], as_s8(bl[kg]), acc[rg][kg], 0, 0, 0);
            // lo*hi
#pragma unroll
            for (int rg = 0; rg < 2; ++rg)
#pragma unroll
                for (int kg = 0; kg < 4; ++kg)
                    acc[rg][kg] = __builtin_amdgcn_mfma_f32_16x16x32_bf16(al[rg], as_s8(bh[kg]), acc[rg][kg], 0, 0, 0);
        }
        // ---- lane-local argmin update (k ascending -> strict < = min-k tie-break) ----
#pragma unroll
        for (int rg = 0; rg < 2; ++rg)
#pragma unroll
            for (int kg = 0; kg < 4; ++kg) {
                const int k = kh * 256 + wk * 64 + kg * 16 + l15;
                const float se = se_l[k];
#pragma unroll
                for (int reg = 0; reg < 4; ++reg) {
                    const int row = wr * 32 + rg * 16 + l4 * 4 + reg;
                    const float d = (f2s[row] + se) - 2.0f * acc[rg][kg][reg];
                    const int i8 = rg * 4 + reg;
                    if (d < bd8[i8]) { bd8[i8] = d; bk8[i8] = k; }
                }
            }
    }

#pragma unroll
    for (int m = 1; m < 16; m <<= 1) {
#pragma unroll
        for (int i = 0; i < 8; ++i) {
            const float od = __shfl_xor(bd8[i], m);
            const int   ok = __shfl_xor(bk8[i], m);
            if (od < bd8[i] || (od == bd8[i] && ok < bk8[i])) { bd8[i] = od; bk8[i] = ok; }
        }
    }
    if (l15 == 0) {
#pragma unroll
        for (int i = 0; i < 8; ++i) {
            const int rg = i >> 2, reg = i & 3;
            const int rr = wr * 32 + rg * 16 + l4 * 4 + reg;
            wbd[wk][rr] = bd8[i]; wbk[wk][rr] = bk8[i];
        }
    }
    __syncthreads();
    if (tid < 64) {
        float bd = wbd[0][tid]; int bk = wbk[0][tid];
#pragma unroll
        for (int q = 1; q < 4; ++q) {
            const float od = wbd[q][tid]; const int ok = wbk[q][tid];
            if (od < bd || (od == bd && ok < bk)) { bd = od; bk = ok; }
        }
        idx_out[h * NROWS + rb * 64 + tid] = bk;
        atomicAdd(&counts[(h << 9) + bk], 1.0f);
    }
}

// ---------------- B: cluster-major segmented sum from planes -> new_emb ------------
__global__ __launch_bounds__(256) void vq_dwseg2(const uint4* __restrict__ planeH,
                                                 const uint4* __restrict__ planeL,
                                                 const int* __restrict__ idx,
                                                 const float* __restrict__ w1,
                                                 const float* __restrict__ w2,
                                                 const float* __restrict__ csf,
                                                 float* __restrict__ nemb) {
    __shared__ ushort rows_l[4][1024];
    __shared__ int cnt_w[4];
    const int tid = threadIdx.x;
    const int h = blockIdx.x >> 9;
    const int k = blockIdx.x & 511;
    const int w = tid >> 6, lane = tid & 63;
    const ushort* pH = (const ushort*)planeH;
    const ushort* pL = (const ushort*)planeL;
    const int c = tid;
    const size_t hbase = (size_t)h * 1024 * 16384;    // ushorts per half
    float acc = 0.f;
    for (int win = 0; win < 4; ++win) {
        {
            const int base = win * 16384 + w * 4096;
            const int* ip = idx + h * NROWS + base;
            int cnt = 0;
            for (int stp = 0; stp < 64; ++stp) {
                const int rl = stp * 64 + lane;
                const bool mt = (ip[rl] == k);
                const unsigned long long m = __ballot(mt);
                if (mt) {
                    const int pos = cnt + __popcll(m & ((1ull << lane) - 1ull));
                    if (pos < 1024) rows_l[w][pos] = (ushort)rl;
                }
                cnt += __popcll(m);
            }
            if (lane == 0) cnt_w[w] = (cnt < 1024) ? cnt : 1024;
        }
        __syncthreads();
        for (int s = 0; s < 4; ++s) {
            const int n = cnt_w[s];
            const int rbase = win * 16384 + s * 4096;
            for (int i = 0; i < n; ++i) {
                const int r = rbase + rows_l[s][i];
                const size_t off = hbase + (size_t)(r >> 6) * 16384 + (r & 63) * 256
                                 + (((c >> 3) ^ (r & 7)) << 3) + (c & 7);
                acc += bf2f(pH[off]) + bf2f(pL[off]);
            }
        }
        __syncthreads();
    }
    const float* wsrc = h ? w2 : w1;
    nemb[((size_t)(h << 9) + k) * SUBD + c] =
        (DECAYF * wsrc[(size_t)k * SUBD + c] + OMDF * acc) / csf[(h << 9) + k];
}

// ---------------- D1: EMA cluster-size smoothing + perplexity ----------------
__global__ void vq_stats(const float* __restrict__ counts,
                         const float* __restrict__ cs_in1,
                         const float* __restrict__ cs_in2,
                         float* __restrict__ cs_final,
                         float* __restrict__ out) {
    __shared__ float red[512];
    const int k = threadIdx.x;
    float perp_tot = 0.f;
    for (int h = 0; h < 2; ++h) {
        const float* csin = h ? cs_in2 : cs_in1;
        float cnt = counts[(h << 9) + k];
        float csn = DECAYF * csin[k] + OMDF * cnt;
        red[k] = csn;
        __syncthreads();
        for (int s = 256; s > 0; s >>= 1) {
            if (k < s) red[k] += red[k + s];
            __syncthreads();
        }
        float n = red[0];
        __syncthreads();
        cs_final[(h << 9) + k] = (csn + EPSF) / (n + 512.0f * EPSF) * n;
        float p = cnt * (1.0f / 65536.0f);
        float e = p * logf(p + 1e-10f);
        red[k] = e;
        __syncthreads();
        for (int s = 256; s > 0; s >>= 1) {
            if (k < s) red[k] += red[k + s];
            __syncthreads();
        }
        if (k == 0) perp_tot += expf(-red[0]);
        __syncthreads();
    }
    if (k == 0) out[33554433] = perp_tot;
}

// ---------------- fallback chain (ws too small for planes) ----------------
__global__ __launch_bounds__(512) void vq_argmin3(const float* __restrict__ x,
                                                  const uint4* __restrict__ embst,
                                                  const float* __restrict__ sume2,
                                                  float* __restrict__ counts,
                                                  int* __restrict__ idx_out) {
    __shared__ uint4 Ah[2048];
    __shared__ uint4 Al[2048];
    __shared__ uint4 Bb[2][2048];
    __shared__ float f2s[64];
    __shared__ float se_l[512];
    __shared__ float wbd[4][64];
    __shared__ int   wbk[4][64];
    const int tid = threadIdx.x;
    const int h  = blockIdx.x & 1;
    const int rb = blockIdx.x >> 1;
    const int b  = rb >> 5;
    const int t0 = (rb & 31) << 6;
    if (tid < 64) f2s[tid] = 0.f;
    se_l[tid] = sume2[h * NK + tid];
    __syncthreads();
    {
        const int r  = tid & 63;
        const int cq = tid >> 6;
        const float* xb = x + ((size_t)b * BD + h * 256) * TT + t0 + r;
        float f2p = 0.f;
#pragma unroll
        for (int it = 0; it < 4; ++it) {
            const int c0 = cq * 32 + it * 8;
            float v[8];
#pragma unroll
            for (int j = 0; j < 8; ++j) v[j] = xb[(size_t)(c0 + j) * TT];
            ushort hi[8], lo[8];
#pragma unroll
            for (int j = 0; j < 8; ++j) {
                hi[j] = f2bf(v[j]);
                lo[j] = f2bf(v[j] - bf2f(hi[j]));
                f2p += v[j] * v[j];
            }
            uint4 uh, ul;
            uh.x = hi[0] | ((uint)hi[1] << 16); uh.y = hi[2] | ((uint)hi[3] << 16);
            uh.z = hi[4] | ((uint)hi[5] << 16); uh.w = hi[6] | ((uint)hi[7] << 16);
            ul.x = lo[0] | ((uint)lo[1] << 16); ul.y = lo[2] | ((uint)lo[3] << 16);
            ul.z = lo[4] | ((uint)lo[5] << 16); ul.w = lo[6] | ((uint)lo[7] << 16);
            const int phys = (c0 >> 3) ^ (r & 7);
            Ah[r * 32 + phys] = uh;
            Al[r * 32 + phys] = ul;
        }
        atomicAdd(&f2s[r], f2p);
    }
    {
        const uint4* src = embst + (size_t)h * 32768;
#pragma unroll
        for (int i = 0; i < 4; ++i) Bb[0][tid + i * 512] = src[tid + i * 512];
    }
    __syncthreads();
    const int l = tid & 63;
    const int wv = tid >> 6;
    const int wr = wv >> 2, wk = wv & 3;
    const int l15 = l & 15, l4 = l >> 4;
    const int bBase = l15 * 4 + (l4 ^ ((l15 >> 1) & 3));
    float bd8[8]; int bk8[8];
#pragma unroll
    for (int i = 0; i < 8; ++i) { bd8[i] = FLT_BIG; bk8[i] = 0; }
    int buf = 0;
    for (int kh = 0; kh < 2; ++kh) {
        f32x4 acc[2][4];
#pragma unroll
        for (int rg = 0; rg < 2; ++rg)
#pragma unroll
            for (int kg = 0; kg < 4; ++kg) acc[rg][kg] = (f32x4)0.f;
        for (int cs = 0; cs < 8; ++cs) {
            const int s = kh * 8 + cs;
            uint4 st[4];
            const bool pf = (s < 15);
            if (pf) {
                const uint4* src = embst + (size_t)h * 32768 + (size_t)(s + 1) * 2048;
#pragma unroll
                for (int i = 0; i < 4; ++i) st[i] = src[tid + i * 512];
            }
            short8 ah[2], al[2];
#pragma unroll
            for (int rg = 0; rg < 2; ++rg) {
                const int row = wr * 32 + rg * 16 + l15;
                const int ia = row * 32 + ((cs * 4 + l4) ^ (row & 7));
                ah[rg] = as_s8(Ah[ia]);
                al[rg] = as_s8(Al[ia]);
            }
            short8 bh[4], bl[4];
#pragma unroll
            for (int kg = 0; kg < 4; ++kg) {
                const int ib = wk * 256 + kg * 64 + bBase;
                bh[kg] = as_s8(Bb[buf][ib]);
                bl[kg] = as_s8(Bb[buf][1024 + ib]);
            }
#pragma unroll
            for (int rg = 0; rg < 2; ++rg)
#pragma unroll
                for (int kg = 0; kg < 4; ++kg) {
                    acc[rg][kg] = __builtin_amdgcn_mfma_f32_16x16x32_bf16(ah[rg], bh[kg], acc[rg][kg], 0, 0, 0);
                    acc[rg][kg] = __builtin_amdgcn_mfma_f32_16x16x32_bf16(ah[rg], bl[kg], acc[rg][kg], 0, 0, 0);
                    acc[rg][kg] = __builtin_amdgcn_mfma_f32_16x16x32_bf16(al[rg], bh[kg], acc[rg][kg], 0, 0, 0);
                }
            if (pf) {
#pragma unroll
                for (int i = 0; i < 4; ++i) Bb[buf ^ 1][tid + i * 512] = st[i];
            }
            __syncthreads();
            buf ^= 1;
        }
#pragma unroll
        for (int rg = 0; rg < 2; ++rg)
#pragma unroll
            for (int kg = 0; kg < 4; ++kg) {
                const int k = kh * 256 + wk * 64 + kg * 16 + l15;
                const float se = se_l[k];
#pragma unroll
                for (int reg = 0; reg < 4; ++reg) {
                    const int row = wr * 32 + rg * 16 + l4 * 4 + reg;
                    const float d = (f2s[row] + se) - 2.0f * acc[rg][kg][reg];
                    const int i8 = rg * 4 + reg;
                    if (d < bd8[i8]) { bd8[i8] = d; bk8[i8] = k; }
                }
            }
    }
#pragma unroll
    for (int m = 1; m < 16; m <<= 1) {
#pragma unroll
        for (int i = 0; i < 8; ++i) {
            const float od = __shfl_xor(bd8[i], m);
            const int   ok = __shfl_xor(bk8[i], m);
            if (od < bd8[i] || (od == bd8[i] && ok < bk8[i])) { bd8[i] = od; bk8[i] = ok; }
        }
    }
    if (l15 == 0) {
#pragma unroll
        for (int i = 0; i < 8; ++i) {
            const int rg = i >> 2, reg = i & 3;
            const int rr = wr * 32 + rg * 16 + l4 * 4 + reg;
            wbd[wk][rr] = bd8[i]; wbk[wk][rr] = bk8[i];
        }
    }
    __syncthreads();
    if (tid < 64) {
        float bd = wbd[0][tid]; int bk = wbk[0][tid];
#pragma unroll
        for (int q = 1; q < 4; ++q) {
            const float od = wbd[q][tid]; const int ok = wbk[q][tid];
            if (od < bd || (od == bd && ok < bk)) { bd = od; bk = ok; }
        }
        idx_out[h * NROWS + b * TT + t0 + tid] = bk;
        atomicAdd(&counts[(h << 9) + bk], 1.0f);
    }
}

__global__ __launch_bounds__(256) void vq_dw(const float* __restrict__ x,
                                             const int* __restrict__ idx,
                                             float* __restrict__ dw) {
    __shared__ float dwp[64 * 512];
    const int tid = threadIdx.x;
    const int h = blockIdx.x & 1;
    const int cr = (blockIdx.x >> 1) & 3;
    const int slab = blockIdx.x >> 3;
#pragma unroll 8
    for (int i = 0; i < 128; ++i) dwp[tid + i * 256] = 0.f;
    __syncthreads();
    for (int it = 0; it < 16; ++it) {
        const int r = (slab << 12) + (it << 8) + tid;
        const int k = idx[(h << 16) + r];
        const float* xb = x + ((size_t)(r >> 11) * BD + (h << 8) + (cr << 6)) * TT + (r & 2047);
#pragma unroll
        for (int c = 0; c < 64; ++c)
            atomicAdd(&dwp[(c << 9) + k], xb[(size_t)c * TT]);
    }
    __syncthreads();
#pragma unroll 8
    for (int i = 0; i < 128; ++i) {
        const int j = tid + i * 256;
        atomicAdd(&dw[(size_t)((h << 9) + (j & 511)) * SUBD + (cr << 6) + (j >> 9)], dwp[j]);
    }
}

__global__ __launch_bounds__(256) void vq_newemb(const float* __restrict__ dw,
                                                 const float* __restrict__ w1,
                                                 const float* __restrict__ w2,
                                                 const float* __restrict__ cs_final,
                                                 float* __restrict__ new_emb) {
    int g = blockIdx.x * 256 + threadIdx.x;
    int h = g >> 15;
    int k = (g >> 6) & 511;
    const float* wi = h ? w2 : w1;
    float4 d4 = *reinterpret_cast<const float4*>(dw + (size_t)g * 4);
    float4 w4 = *reinterpret_cast<const float4*>(wi + (size_t)(g & 32767) * 4);
    float cs = cs_final[(h << 9) + k];
    float4 o;
    o.x = (DECAYF * w4.x + OMDF * d4.x) / cs;
    o.y = (DECAYF * w4.y + OMDF * d4.y) / cs;
    o.z = (DECAYF * w4.z + OMDF * d4.z) / cs;
    o.w = (DECAYF * w4.w + OMDF * d4.w) / cs;
    *reinterpret_cast<float4*>(new_emb + (size_t)g * 4) = o;
}

// ---------------- E: gather + output + vq_loss ----------------
__global__ __launch_bounds__(256) void vq_out(const float* __restrict__ x,
                                              const float* __restrict__ nemb,
                                              const int* __restrict__ idx,
                                              float* __restrict__ out) {
    __shared__ int idx_l[2][64];
    __shared__ float wsum[4];
    const int tid = threadIdx.x;
    const int b = blockIdx.x >> 5;
    const int t0 = (blockIdx.x & 31) << 6;
    if (tid < 128) {
        int hh = tid >> 6, t = tid & 63;
        idx_l[hh][t] = idx[hh * NROWS + b * TT + t0 + t];
    }
    __syncthreads();
    const int tq = tid & 15;
    const int cw = tid >> 4;
    const int k0 = idx_l[0][tq * 4 + 0], k1 = idx_l[0][tq * 4 + 1];
    const int k2 = idx_l[0][tq * 4 + 2], k3 = idx_l[0][tq * 4 + 3];
    const int m0 = idx_l[1][tq * 4 + 0], m1 = idx_l[1][tq * 4 + 1];
    const int m2 = idx_l[1][tq * 4 + 2], m3 = idx_l[1][tq * 4 + 3];
    float lsum = 0.f;
    for (int i = 0; i < 32; ++i) {
        const int c = cw + i * 16;
        const int hh = c >> 8, cp = c & 255;
        const size_t base = ((size_t)b * BD + c) * TT + t0 + tq * 4;
        float4 xv = *reinterpret_cast<const float4*>(x + base);
        const size_t eb = (size_t)(hh << 9) * SUBD + cp;
        float q0 = nemb[eb + (size_t)(hh ? m0 : k0) * SUBD];
        float q1 = nemb[eb + (size_t)(hh ? m1 : k1) * SUBD];
        float q2 = nemb[eb + (size_t)(hh ? m2 : k2) * SUBD];
        float q3 = nemb[eb + (size_t)(hh ? m3 : k3) * SUBD];
        float4 o; float t1;
        t1 = q0 - xv.x; o.x = xv.x + t1; lsum += t1 * t1;
        t1 = q1 - xv.y; o.y = xv.y + t1; lsum += t1 * t1;
        t1 = q2 - xv.z; o.z = xv.z + t1; lsum += t1 * t1;
        t1 = q3 - xv.w; o.w = xv.w + t1; lsum += t1 * t1;
        *reinterpret_cast<float4*>(out + base) = o;
    }
#pragma unroll
    for (int m = 1; m < 64; m <<= 1) lsum += __shfl_xor(lsum, m);
    if ((tid & 63) == 0) wsum[tid >> 6] = lsum;
    __syncthreads();
    if (tid == 0) {
        float s = wsum[0] + wsum[1] + wsum[2] + wsum[3];
        atomicAdd(out + 33554432, s * (0.25f / 33554432.0f));
    }
}

extern "C" void kernel_launch(void* const* d_in, const int* in_sizes, int n_in,
                              void* d_out, int out_size, void* d_ws, size_t ws_size,
                              hipStream_t stream) {
    const float* x    = (const float*)d_in[0];
    const float* emb1 = (const float*)d_in[1];
    const float* emb2 = (const float*)d_in[2];
    const float* cs1  = (const float*)d_in[3];
    const float* w1   = (const float*)d_in[4];
    const float* cs2  = (const float*)d_in[5];
    const float* w2   = (const float*)d_in[6];
    float* out = (float*)d_out;
    float* ws  = (float*)d_ws;

    float* counts = ws;                     // 1024
    float* csf    = ws + 1024;              // 1024
    float* se2    = ws + 2048;              // 1024
    float* nemb   = ws + 3072;              // 262144
    int*   idx    = (int*)(ws + 265216);    // 131072 ints
    uint4* embst  = (uint4*)(ws + 396288);  // 65536 uint4 (1 MB)
    float* f2g    = ws + 658432;            // 131072
    uint4* planeH = (uint4*)(ws + 789504);  // 4M uint4 (64 MB)
    uint4* planeL = (uint4*)(ws + 17566720);// 4M uint4 (64 MB)
    float* dw     = ws + 789504;            // fallback only (overlaps planeH)

    const size_t NEED = (size_t)(789504 + 2 * 16777216) * 4;
    const bool fast = (ws_size >= NEED);

    hipMemsetAsync(counts, 0, 1024 * sizeof(float), stream);
    hipMemsetAsync(out + 33554432, 0, 2 * sizeof(float), stream);

    vq_sume2 <<<4,   256, 0, stream>>>(emb1, emb2, se2);
    vq_embcvt<<<256, 256, 0, stream>>>(emb1, emb2, embst);

    if (fast) {
        vq_x1     <<<2048, 512, 0, stream>>>(x, planeH, planeL, f2g);
        vq_argmin5<<<2048, 512, 0, stream>>>(planeH, planeL, embst, f2g, se2, counts, idx);
        vq_stats  <<<1,    512, 0, stream>>>(counts, cs1, cs2, csf, out);
        vq_dwseg2 <<<1024, 256, 0, stream>>>(planeH, planeL, idx, w1, w2, csf, nemb);
    } else {
        hipMemsetAsync(dw, 0, 262144 * sizeof(float), stream);
        vq_argmin3<<<2048, 512, 0, stream>>>(x, embst, se2, counts, idx);
        vq_dw     <<<128,  256, 0, stream>>>(x, idx, dw);
        vq_stats  <<<1,    512, 0, stream>>>(counts, cs1, cs2, csf, out);
        vq_newemb <<<256,  256, 0, stream>>>(dw, w1, w2, csf, nemb);
    }
    vq_out<<<1024, 256, 0, stream>>>(x, nemb, idx, out);
}

// Round 8
// 346.126 us; speedup vs baseline: 1.4875x; 1.0416x over previous
//
#include <hip/hip_runtime.h>

typedef short short8 __attribute__((ext_vector_type(8)));
typedef float f32x4 __attribute__((ext_vector_type(4)));

#define NK 512
#define SUBD 256
#define TT 2048
#define BD 512
#define NROWS 65536
#define DECAYF 0.99f
#define OMDF 0.01f
#define EPSF 1e-5f
#define FLT_BIG 3.402823466e+38f

static __device__ __forceinline__ ushort f2bf(float f) {
    uint u = __float_as_uint(f);
    u += 0x7FFFu + ((u >> 16) & 1u);
    return (ushort)(u >> 16);
}
static __device__ __forceinline__ float bf2f(ushort h) {
    return __uint_as_float(((uint)h) << 16);
}
union UCast { uint4 u; short8 s; };
static __device__ __forceinline__ short8 as_s8(uint4 v) { UCast c; c.u = v; return c.s; }

// async global->LDS, 16B per lane; LDS dest must be wave-uniform base (+lane*16)
static __device__ __forceinline__ void gload_lds16(const uint4* g, uint4* l) {
    __builtin_amdgcn_global_load_lds(
        (const __attribute__((address_space(1))) void*)g,
        (__attribute__((address_space(3))) void*)l, 16, 0, 0);
}

// ---------------- P0: sume2[h][k] = sum_c emb[k][c]^2 (exact fp32) ----------------
__global__ __launch_bounds__(256) void vq_sume2(const float* __restrict__ emb1,
                                                const float* __restrict__ emb2,
                                                float* __restrict__ sume2) {
    int r = blockIdx.x * 256 + threadIdx.x;
    const float* e = (r >> 9) ? emb2 : emb1;
    const float* row = e + (size_t)(r & 511) * SUBD;
    float s = 0.f;
#pragma unroll 8
    for (int i = 0; i < 64; ++i) {
        float4 v = *reinterpret_cast<const float4*>(row + i * 4);
        s += v.x * v.x + v.y * v.y + v.z * v.z + v.w * v.w;
    }
    sume2[r] = s;
}

// ---------------- P1: emb -> split-bf16, pre-swizzled staged layout ----------------
// embst[h][s=kh*8+cs][spl][k 0..255][pg 0..3]; phys pg holds logical group pg^((k>>1)&3)
__global__ __launch_bounds__(256) void vq_embcvt(const float* __restrict__ emb1,
                                                 const float* __restrict__ emb2,
                                                 uint4* __restrict__ embst) {
    int id = blockIdx.x * 256 + threadIdx.x;      // 0..65535
    int h   = id >> 15;
    int s   = (id >> 11) & 15;
    int spl = (id >> 10) & 1;
    int k   = (id >> 2) & 255;
    int gp  = id & 3;
    int kh = s >> 3, cs = s & 7;
    int gl = gp ^ ((k >> 1) & 3);                 // un-swizzle to logical c-group
    const float* e = h ? emb2 : emb1;
    const float* src = e + (size_t)(kh * 256 + k) * SUBD + cs * 32 + gl * 8;
    float4 v0 = *reinterpret_cast<const float4*>(src);
    float4 v1 = *reinterpret_cast<const float4*>(src + 4);
    float f[8] = {v0.x, v0.y, v0.z, v0.w, v1.x, v1.y, v1.z, v1.w};
    ushort o[8];
#pragma unroll
    for (int i = 0; i < 8; ++i) {
        ushort hh = f2bf(f[i]);
        o[i] = spl ? f2bf(f[i] - bf2f(hh)) : hh;
    }
    uint4 d;
    d.x = o[0] | ((uint)o[1] << 16);
    d.y = o[2] | ((uint)o[3] << 16);
    d.z = o[4] | ((uint)o[5] << 16);
    d.w = o[6] | ((uint)o[7] << 16);
    embst[id] = d;
}

// ---------------- A: fused convert + argmin + plane dump ----------------
// grid 2048 = (rblk,h); 512 thr = 8 waves (2 wr x 4 wk); wave tile 32r x 64k.
// Phase 1: read x, split-bf16 -> LDS (x1 layout) + global planes + deterministic f2.
// Phase 2: barrier-free MFMA loop, B streamed global->regs from embst.
__global__ __launch_bounds__(512, 2) void vq_argmin6(const float* __restrict__ x,
                                                     const uint4* __restrict__ embst,
                                                     const float* __restrict__ sume2,
                                                     float* __restrict__ counts,
                                                     int* __restrict__ idx_out,
                                                     uint4* __restrict__ planeH,
                                                     uint4* __restrict__ planeL) {
    __shared__ uint4 Ah[2048];        // 32 KB
    __shared__ uint4 Al[2048];        // 32 KB
    __shared__ float f2p[512];
    __shared__ float f2s[64];
    __shared__ float se_l[512];
    __shared__ float wbd[4][64];
    __shared__ int   wbk[4][64];

    const int tid = threadIdx.x;
    const int h  = blockIdx.x & 1;
    const int rb = blockIdx.x >> 1;
    const int b  = rb >> 5;
    const int t0 = (rb & 31) << 6;
    const int wv = tid >> 6;
    const int lane = tid & 63;

    se_l[tid] = sume2[h * NK + tid];

    // ---- phase 1: transpose/convert x -> LDS planes (+f2 partials) ----
    {
        const int r  = lane;
        const int co = wv * 32;
        const float* xb = x + ((size_t)b * BD + h * 256 + co) * TT + t0 + r;
        float f2 = 0.f;
#pragma unroll
        for (int j4 = 0; j4 < 4; ++j4) {
            float v[8];
#pragma unroll
            for (int j = 0; j < 8; ++j) v[j] = xb[(size_t)(j4 * 8 + j) * TT];
            ushort hi[8], lo[8];
#pragma unroll
            for (int j = 0; j < 8; ++j) {
                hi[j] = f2bf(v[j]);
                lo[j] = f2bf(v[j] - bf2f(hi[j]));
                f2 += v[j] * v[j];
            }
            uint4 uh, ul;
            uh.x = hi[0] | ((uint)hi[1] << 16); uh.y = hi[2] | ((uint)hi[3] << 16);
            uh.z = hi[4] | ((uint)hi[5] << 16); uh.w = hi[6] | ((uint)hi[7] << 16);
            ul.x = lo[0] | ((uint)lo[1] << 16); ul.y = lo[2] | ((uint)lo[3] << 16);
            ul.z = lo[4] | ((uint)lo[5] << 16); ul.w = lo[6] | ((uint)lo[7] << 16);
            const int chunk = (co >> 3) + j4;
            const int phys = chunk ^ (r & 7);
            Ah[r * 32 + phys] = uh;
            Al[r * 32 + phys] = ul;
        }
        f2p[tid] = f2;
    }
    __syncthreads();

    // ---- deterministic f2 reduce + coalesced plane write-out (for vq_dwseg2) ----
    if (tid < 64) {
        float s = 0.f;
#pragma unroll
        for (int g = 0; g < 8; ++g) s += f2p[g * 64 + tid];   // ascending c order
        f2s[tid] = s;
    }
    {
        const size_t pb = (size_t)(h * 1024 + rb) * 2048;
#pragma unroll
        for (int i = 0; i < 4; ++i) {
            planeH[pb + tid + i * 512] = Ah[tid + i * 512];
            planeL[pb + tid + i * 512] = Al[tid + i * 512];
        }
    }
    __syncthreads();

    // ---- phase 2: barrier-free MFMA loop (B streamed from L2) ----
    const int l15 = lane & 15, l4 = lane >> 4;
    const int wr = wv >> 2, wk = wv & 3;
    const uint4* eb = embst + (size_t)h * 32768;
    const int bLane = wk * 256 + l15 * 4 + (l4 ^ ((l15 >> 1) & 3));

    float bd8[8]; int bk8[8];
#pragma unroll
    for (int i = 0; i < 8; ++i) { bd8[i] = FLT_BIG; bk8[i] = 0; }

#pragma unroll 1
    for (int kh = 0; kh < 2; ++kh) {
        f32x4 acc[2][4];
#pragma unroll
        for (int rg = 0; rg < 2; ++rg)
#pragma unroll
            for (int kg = 0; kg < 4; ++kg) acc[rg][kg] = (f32x4)0.f;

#pragma unroll 1
        for (int cs = 0; cs < 8; ++cs) {
            const int s = kh * 8 + cs;
            uint4 bh[4], bl[4];
#pragma unroll
            for (int kg = 0; kg < 4; ++kg)
                bh[kg] = eb[(size_t)s * 2048 + bLane + kg * 64];
#pragma unroll
            for (int kg = 0; kg < 4; ++kg)
                bl[kg] = eb[(size_t)s * 2048 + 1024 + bLane + kg * 64];
            short8 ah[2], al[2];
#pragma unroll
            for (int rg = 0; rg < 2; ++rg) {
                const int row = wr * 32 + rg * 16 + l15;
                const int ia = row * 32 + ((cs * 4 + l4) ^ (row & 7));
                ah[rg] = as_s8(Ah[ia]);
                al[rg] = as_s8(Al[ia]);
            }
#pragma unroll
            for (int rg = 0; rg < 2; ++rg)
#pragma unroll
                for (int kg = 0; kg < 4; ++kg)
                    acc[rg][kg] = __builtin_amdgcn_mfma_f32_16x16x32_bf16(ah[rg], as_s8(bh[kg]), acc[rg][kg], 0, 0, 0);
#pragma unroll
            for (int rg = 0; rg < 2; ++rg)
#pragma unroll
                for (int kg = 0; kg < 4; ++kg)
                    acc[rg][kg] = __builtin_amdgcn_mfma_f32_16x16x32_bf16(ah[rg], as_s8(bl[kg]), acc[rg][kg], 0, 0, 0);
#pragma unroll
            for (int rg = 0; rg < 2; ++rg)
#pragma unroll
                for (int kg = 0; kg < 4; ++kg)
                    acc[rg][kg] = __builtin_amdgcn_mfma_f32_16x16x32_bf16(al[rg], as_s8(bh[kg]), acc[rg][kg], 0, 0, 0);
        }
        // ---- lane-local argmin update (k ascending -> strict < = min-k tie-break) ----
#pragma unroll
        for (int rg = 0; rg < 2; ++rg)
#pragma unroll
            for (int kg = 0; kg < 4; ++kg) {
                const int k = kh * 256 + wk * 64 + kg * 16 + l15;
                const float se = se_l[k];
#pragma unroll
                for (int reg = 0; reg < 4; ++reg) {
                    const int row = wr * 32 + rg * 16 + l4 * 4 + reg;
                    const float d = (f2s[row] + se) - 2.0f * acc[rg][kg][reg];
                    const int i8 = rg * 4 + reg;
                    if (d < bd8[i8]) { bd8[i8] = d; bk8[i8] = k; }
                }
            }
    }

#pragma unroll
    for (int m = 1; m < 16; m <<= 1) {
#pragma unroll
        for (int i = 0; i < 8; ++i) {
            const float od = __shfl_xor(bd8[i], m);
            const int   ok = __shfl_xor(bk8[i], m);
            if (od < bd8[i] || (od == bd8[i] && ok < bk8[i])) { bd8[i] = od; bk8[i] = ok; }
        }
    }
    if (l15 == 0) {
#pragma unroll
        for (int i = 0; i < 8; ++i) {
            const int rg = i >> 2, reg = i & 3;
            const int rr = wr * 32 + rg * 16 + l4 * 4 + reg;
            wbd[wk][rr] = bd8[i]; wbk[wk][rr] = bk8[i];
        }
    }
    __syncthreads();
    if (tid < 64) {
        float bd = wbd[0][tid]; int bk = wbk[0][tid];
#pragma unroll
        for (int q = 1; q < 4; ++q) {
            const float od = wbd[q][tid]; const int ok = wbk[q][tid];
            if (od < bd || (od == bd && ok < bk)) { bd = od; bk = ok; }
        }
        idx_out[h * NROWS + rb * 64 + tid] = bk;
        atomicAdd(&counts[(h << 9) + bk], 1.0f);
    }
}

// ---------------- B: cluster-major segmented sum from planes -> new_emb ------------
__global__ __launch_bounds__(256) void vq_dwseg2(const uint4* __restrict__ planeH,
                                                 const uint4* __restrict__ planeL,
                                                 const int* __restrict__ idx,
                                                 const float* __restrict__ w1,
                                                 const float* __restrict__ w2,
                                                 const float* __restrict__ csf,
                                                 float* __restrict__ nemb) {
    __shared__ ushort rows_l[4][1024];
    __shared__ int cnt_w[4];
    const int tid = threadIdx.x;
    const int h = blockIdx.x >> 9;
    const int k = blockIdx.x & 511;
    const int w = tid >> 6, lane = tid & 63;
    const ushort* pH = (const ushort*)planeH;
    const ushort* pL = (const ushort*)planeL;
    const int c = tid;
    const size_t hbase = (size_t)h * 1024 * 16384;    // ushorts per half
    float acc = 0.f;
    for (int win = 0; win < 4; ++win) {
        {
            const int base = win * 16384 + w * 4096;
            const int* ip = idx + h * NROWS + base;
            int cnt = 0;
            for (int stp = 0; stp < 64; ++stp) {
                const int rl = stp * 64 + lane;
                const bool mt = (ip[rl] == k);
                const unsigned long long m = __ballot(mt);
                if (mt) {
                    const int pos = cnt + __popcll(m & ((1ull << lane) - 1ull));
                    if (pos < 1024) rows_l[w][pos] = (ushort)rl;
                }
                cnt += __popcll(m);
            }
            if (lane == 0) cnt_w[w] = (cnt < 1024) ? cnt : 1024;
        }
        __syncthreads();
        for (int s = 0; s < 4; ++s) {
            const int n = cnt_w[s];
            const int rbase = win * 16384 + s * 4096;
            for (int i = 0; i < n; ++i) {
                const int r = rbase + rows_l[s][i];
                const size_t off = hbase + (size_t)(r >> 6) * 16384 + (r & 63) * 256
                                 + (((c >> 3) ^ (r & 7)) << 3) + (c & 7);
                acc += bf2f(pH[off]) + bf2f(pL[off]);
            }
        }
        __syncthreads();
    }
    const float* wsrc = h ? w2 : w1;
    nemb[((size_t)(h << 9) + k) * SUBD + c] =
        (DECAYF * wsrc[(size_t)k * SUBD + c] + OMDF * acc) / csf[(h << 9) + k];
}

// ---------------- D1: EMA cluster-size smoothing + perplexity ----------------
__global__ void vq_stats(const float* __restrict__ counts,
                         const float* __restrict__ cs_in1,
                         const float* __restrict__ cs_in2,
                         float* __restrict__ cs_final,
                         float* __restrict__ out) {
    __shared__ float red[512];
    const int k = threadIdx.x;
    float perp_tot = 0.f;
    for (int h = 0; h < 2; ++h) {
        const float* csin = h ? cs_in2 : cs_in1;
        float cnt = counts[(h << 9) + k];
        float csn = DECAYF * csin[k] + OMDF * cnt;
        red[k] = csn;
        __syncthreads();
        for (int s = 256; s > 0; s >>= 1) {
            if (k < s) red[k] += red[k + s];
            __syncthreads();
        }
        float n = red[0];
        __syncthreads();
        cs_final[(h << 9) + k] = (csn + EPSF) / (n + 512.0f * EPSF) * n;
        float p = cnt * (1.0f / 65536.0f);
        float e = p * logf(p + 1e-10f);
        red[k] = e;
        __syncthreads();
        for (int s = 256; s > 0; s >>= 1) {
            if (k < s) red[k] += red[k + s];
            __syncthreads();
        }
        if (k == 0) perp_tot += expf(-red[0]);
        __syncthreads();
    }
    if (k == 0) out[33554433] = perp_tot;
}

// ---------------- fallback chain (ws too small for planes) ----------------
__global__ __launch_bounds__(512) void vq_argmin3(const float* __restrict__ x,
                                                  const uint4* __restrict__ embst,
                                                  const float* __restrict__ sume2,
                                                  float* __restrict__ counts,
                                                  int* __restrict__ idx_out) {
    __shared__ uint4 Ah[2048];
    __shared__ uint4 Al[2048];
    __shared__ uint4 Bb[2][2048];
    __shared__ float f2s[64];
    __shared__ float se_l[512];
    __shared__ float wbd[4][64];
    __shared__ int   wbk[4][64];
    const int tid = threadIdx.x;
    const int h  = blockIdx.x & 1;
    const int rb = blockIdx.x >> 1;
    const int b  = rb >> 5;
    const int t0 = (rb & 31) << 6;
    if (tid < 64) f2s[tid] = 0.f;
    se_l[tid] = sume2[h * NK + tid];
    __syncthreads();
    {
        const int r  = tid & 63;
        const int cq = tid >> 6;
        const float* xb = x + ((size_t)b * BD + h * 256) * TT + t0 + r;
        float f2p = 0.f;
#pragma unroll
        for (int it = 0; it < 4; ++it) {
            const int c0 = cq * 32 + it * 8;
            float v[8];
#pragma unroll
            for (int j = 0; j < 8; ++j) v[j] = xb[(size_t)(c0 + j) * TT];
            ushort hi[8], lo[8];
#pragma unroll
            for (int j = 0; j < 8; ++j) {
                hi[j] = f2bf(v[j]);
                lo[j] = f2bf(v[j] - bf2f(hi[j]));
                f2p += v[j] * v[j];
            }
            uint4 uh, ul;
            uh.x = hi[0] | ((uint)hi[1] << 16); uh.y = hi[2] | ((uint)hi[3] << 16);
            uh.z = hi[4] | ((uint)hi[5] << 16); uh.w = hi[6] | ((uint)hi[7] << 16);
            ul.x = lo[0] | ((uint)lo[1] << 16); ul.y = lo[2] | ((uint)lo[3] << 16);
            ul.z = lo[4] | ((uint)lo[5] << 16); ul.w = lo[6] | ((uint)lo[7] << 16);
            const int phys = (c0 >> 3) ^ (r & 7);
            Ah[r * 32 + phys] = uh;
            Al[r * 32 + phys] = ul;
        }
        atomicAdd(&f2s[r], f2p);
    }
    {
        const uint4* src = embst + (size_t)h * 32768;
#pragma unroll
        for (int i = 0; i < 4; ++i) Bb[0][tid + i * 512] = src[tid + i * 512];
    }
    __syncthreads();
    const int l = tid & 63;
    const int wv = tid >> 6;
    const int wr = wv >> 2, wk = wv & 3;
    const int l15 = l & 15, l4 = l >> 4;
    const int bBase = l15 * 4 + (l4 ^ ((l15 >> 1) & 3));
    float bd8[8]; int bk8[8];
#pragma unroll
    for (int i = 0; i < 8; ++i) { bd8[i] = FLT_BIG; bk8[i] = 0; }
    int buf = 0;
    for (int kh = 0; kh < 2; ++kh) {
        f32x4 acc[2][4];
#pragma unroll
        for (int rg = 0; rg < 2; ++rg)
#pragma unroll
            for (int kg = 0; kg < 4; ++kg) acc[rg][kg] = (f32x4)0.f;
        for (int cs = 0; cs < 8; ++cs) {
            const int s = kh * 8 + cs;
            uint4 st[4];
            const bool pf = (s < 15);
            if (pf) {
                const uint4* src = embst + (size_t)h * 32768 + (size_t)(s + 1) * 2048;
#pragma unroll
                for (int i = 0; i < 4; ++i) st[i] = src[tid + i * 512];
            }
            short8 ah[2], al[2];
#pragma unroll
            for (int rg = 0; rg < 2; ++rg) {
                const int row = wr * 32 + rg * 16 + l15;
                const int ia = row * 32 + ((cs * 4 + l4) ^ (row & 7));
                ah[rg] = as_s8(Ah[ia]);
                al[rg] = as_s8(Al[ia]);
            }
            short8 bh[4], bl[4];
#pragma unroll
            for (int kg = 0; kg < 4; ++kg) {
                const int ib = wk * 256 + kg * 64 + bBase;
                bh[kg] = as_s8(Bb[buf][ib]);
                bl[kg] = as_s8(Bb[buf][1024 + ib]);
            }
#pragma unroll
            for (int rg = 0; rg < 2; ++rg)
#pragma unroll
                for (int kg = 0; kg < 4; ++kg) {
                    acc[rg][kg] = __builtin_amdgcn_mfma_f32_16x16x32_bf16(ah[rg], bh[kg], acc[rg][kg], 0, 0, 0);
                    acc[rg][kg] = __builtin_amdgcn_mfma_f32_16x16x32_bf16(ah[rg], bl[kg], acc[rg][kg], 0, 0, 0);
                    acc[rg][kg] = __builtin_amdgcn_mfma_f32_16x16x32_bf16(al[rg], bh[kg], acc[rg][kg], 0, 0, 0);
                }
            if (pf) {
#pragma unroll
                for (int i = 0; i < 4; ++i) Bb[buf ^ 1][tid + i * 512] = st[i];
            }
            __syncthreads();
            buf ^= 1;
        }
#pragma unroll
        for (int rg = 0; rg < 2; ++rg)
#pragma unroll
            for (int kg = 0; kg < 4; ++kg) {
                const int k = kh * 256 + wk * 64 + kg * 16 + l15;
                const float se = se_l[k];
#pragma unroll
                for (int reg = 0; reg < 4; ++reg) {
                    const int row = wr * 32 + rg * 16 + l4 * 4 + reg;
                    const float d = (f2s[row] + se) - 2.0f * acc[rg][kg][reg];
                    const int i8 = rg * 4 + reg;
                    if (d < bd8[i8]) { bd8[i8] = d; bk8[i8] = k; }
                }
            }
    }
#pragma unroll
    for (int m = 1; m < 16; m <<= 1) {
#pragma unroll
        for (int i = 0; i < 8; ++i) {
            const float od = __shfl_xor(bd8[i], m);
            const int   ok = __shfl_xor(bk8[i], m);
            if (od < bd8[i] || (od == bd8[i] && ok < bk8[i])) { bd8[i] = od; bk8[i] = ok; }
        }
    }
    if (l15 == 0) {
#pragma unroll
        for (int i = 0; i < 8; ++i) {
            const int rg = i >> 2, reg = i & 3;
            const int rr = wr * 32 + rg * 16 + l4 * 4 + reg;
            wbd[wk][rr] = bd8[i]; wbk[wk][rr] = bk8[i];
        }
    }
    __syncthreads();
    if (tid < 64) {
        float bd = wbd[0][tid]; int bk = wbk[0][tid];
#pragma unroll
        for (int q = 1; q < 4; ++q) {
            const float od = wbd[q][tid]; const int ok = wbk[q][tid];
            if (od < bd || (od == bd && ok < bk)) { bd = od; bk = ok; }
        }
        idx_out[h * NROWS + b * TT + t0 + tid] = bk;
        atomicAdd(&counts[(h << 9) + bk], 1.0f);
    }
}

__global__ __launch_bounds__(256) void vq_dw(const float* __restrict__ x,
                                             const int* __restrict__ idx,
                                             float* __restrict__ dw) {
    __shared__ float dwp[64 * 512];
    const int tid = threadIdx.x;
    const int h = blockIdx.x & 1;
    const int cr = (blockIdx.x >> 1) & 3;
    const int slab = blockIdx.x >> 3;
#pragma unroll 8
    for (int i = 0; i < 128; ++i) dwp[tid + i * 256] = 0.f;
    __syncthreads();
    for (int it = 0; it < 16; ++it) {
        const int r = (slab << 12) + (it << 8) + tid;
        const int k = idx[(h << 16) + r];
        const float* xb = x + ((size_t)(r >> 11) * BD + (h << 8) + (cr << 6)) * TT + (r & 2047);
#pragma unroll
        for (int c = 0; c < 64; ++c)
            atomicAdd(&dwp[(c << 9) + k], xb[(size_t)c * TT]);
    }
    __syncthreads();
#pragma unroll 8
    for (int i = 0; i < 128; ++i) {
        const int j = tid + i * 256;
        atomicAdd(&dw[(size_t)((h << 9) + (j & 511)) * SUBD + (cr << 6) + (j >> 9)], dwp[j]);
    }
}

__global__ __launch_bounds__(256) void vq_newemb(const float* __restrict__ dw,
                                                 const float* __restrict__ w1,
                                                 const float* __restrict__ w2,
                                                 const float* __restrict__ cs_final,
                                                 float* __restrict__ new_emb) {
    int g = blockIdx.x * 256 + threadIdx.x;
    int h = g >> 15;
    int k = (g >> 6) & 511;
    const float* wi = h ? w2 : w1;
    float4 d4 = *reinterpret_cast<const float4*>(dw + (size_t)g * 4);
    float4 w4 = *reinterpret_cast<const float4*>(wi + (size_t)(g & 32767) * 4);
    float cs = cs_final[(h << 9) + k];
    float4 o;
    o.x = (DECAYF * w4.x + OMDF * d4.x) / cs;
    o.y = (DECAYF * w4.y + OMDF * d4.y) / cs;
    o.z = (DECAYF * w4.z + OMDF * d4.z) / cs;
    o.w = (DECAYF * w4.w + OMDF * d4.w) / cs;
    *reinterpret_cast<float4*>(new_emb + (size_t)g * 4) = o;
}

// ---------------- E: gather + output + vq_loss ----------------
__global__ __launch_bounds__(256) void vq_out(const float* __restrict__ x,
                                              const float* __restrict__ nemb,
                                              const int* __restrict__ idx,
                                              float* __restrict__ out) {
    __shared__ int idx_l[2][64];
    __shared__ float wsum[4];
    const int tid = threadIdx.x;
    const int b = blockIdx.x >> 5;
    const int t0 = (blockIdx.x & 31) << 6;
    if (tid < 128) {
        int hh = tid >> 6, t = tid & 63;
        idx_l[hh][t] = idx[hh * NROWS + b * TT + t0 + t];
    }
    __syncthreads();
    const int tq = tid & 15;
    const int cw = tid >> 4;
    const int k0 = idx_l[0][tq * 4 + 0], k1 = idx_l[0][tq * 4 + 1];
    const int k2 = idx_l[0][tq * 4 + 2], k3 = idx_l[0][tq * 4 + 3];
    const int m0 = idx_l[1][tq * 4 + 0], m1 = idx_l[1][tq * 4 + 1];
    const int m2 = idx_l[1][tq * 4 + 2], m3 = idx_l[1][tq * 4 + 3];
    float lsum = 0.f;
    for (int i = 0; i < 32; ++i) {
        const int c = cw + i * 16;
        const int hh = c >> 8, cp = c & 255;
        const size_t base = ((size_t)b * BD + c) * TT + t0 + tq * 4;
        float4 xv = *reinterpret_cast<const float4*>(x + base);
        const size_t eb = (size_t)(hh << 9) * SUBD + cp;
        float q0 = nemb[eb + (size_t)(hh ? m0 : k0) * SUBD];
        float q1 = nemb[eb + (size_t)(hh ? m1 : k1) * SUBD];
        float q2 = nemb[eb + (size_t)(hh ? m2 : k2) * SUBD];
        float q3 = nemb[eb + (size_t)(hh ? m3 : k3) * SUBD];
        float4 o; float t1;
        t1 = q0 - xv.x; o.x = xv.x + t1; lsum += t1 * t1;
        t1 = q1 - xv.y; o.y = xv.y + t1; lsum += t1 * t1;
        t1 = q2 - xv.z; o.z = xv.z + t1; lsum += t1 * t1;
        t1 = q3 - xv.w; o.w = xv.w + t1; lsum += t1 * t1;
        *reinterpret_cast<float4*>(out + base) = o;
    }
#pragma unroll
    for (int m = 1; m < 64; m <<= 1) lsum += __shfl_xor(lsum, m);
    if ((tid & 63) == 0) wsum[tid >> 6] = lsum;
    __syncthreads();
    if (tid == 0) {
        float s = wsum[0] + wsum[1] + wsum[2] + wsum[3];
        atomicAdd(out + 33554432, s * (0.25f / 33554432.0f));
    }
}

extern "C" void kernel_launch(void* const* d_in, const int* in_sizes, int n_in,
                              void* d_out, int out_size, void* d_ws, size_t ws_size,
                              hipStream_t stream) {
    const float* x    = (const float*)d_in[0];
    const float* emb1 = (const float*)d_in[1];
    const float* emb2 = (const float*)d_in[2];
    const float* cs1  = (const float*)d_in[3];
    const float* w1   = (const float*)d_in[4];
    const float* cs2  = (const float*)d_in[5];
    const float* w2   = (const float*)d_in[6];
    float* out = (float*)d_out;
    float* ws  = (float*)d_ws;

    float* counts = ws;                     // 1024
    float* csf    = ws + 1024;              // 1024
    float* se2    = ws + 2048;              // 1024
    float* nemb   = ws + 3072;              // 262144
    int*   idx    = (int*)(ws + 265216);    // 131072 ints
    uint4* embst  = (uint4*)(ws + 396288);  // 65536 uint4 (1 MB)
    uint4* planeH = (uint4*)(ws + 789504);  // 4M uint4 (64 MB)
    uint4* planeL = (uint4*)(ws + 17566720);// 4M uint4 (64 MB)
    float* dw     = ws + 789504;            // fallback only (overlaps planeH)

    const size_t NEED = (size_t)(789504 + 2 * 16777216) * 4;
    const bool fast = (ws_size >= NEED);

    hipMemsetAsync(counts, 0, 1024 * sizeof(float), stream);
    hipMemsetAsync(out + 33554432, 0, 2 * sizeof(float), stream);

    vq_sume2 <<<4,   256, 0, stream>>>(emb1, emb2, se2);
    vq_embcvt<<<256, 256, 0, stream>>>(emb1, emb2, embst);

    if (fast) {
        vq_argmin6<<<2048, 512, 0, stream>>>(x, embst, se2, counts, idx, planeH, planeL);
        vq_stats  <<<1,    512, 0, stream>>>(counts, cs1, cs2, csf, out);
        vq_dwseg2 <<<1024, 256, 0, stream>>>(planeH, planeL, idx, w1, w2, csf, nemb);
    } else {
        hipMemsetAsync(dw, 0, 262144 * sizeof(float), stream);
        vq_argmin3<<<2048, 512, 0, stream>>>(x, embst, se2, counts, idx);
        vq_dw     <<<128,  256, 0, stream>>>(x, idx, dw);
        vq_stats  <<<1,    512, 0, stream>>>(counts, cs1, cs2, csf, out);
        vq_newemb <<<256,  256, 0, stream>>>(dw, w1, w2, csf, nemb);
    }
    vq_out<<<1024, 256, 0, stream>>>(x, nemb, idx, out);
}

// Round 9
// 324.682 us; speedup vs baseline: 1.5857x; 1.0660x over previous
//
#include <hip/hip_runtime.h>

typedef short short8 __attribute__((ext_vector_type(8)));
typedef float f32x4 __attribute__((ext_vector_type(4)));

#define NK 512
#define SUBD 256
#define TT 2048
#define BD 512
#define NROWS 65536
#define DECAYF 0.99f
#define OMDF 0.01f
#define EPSF 1e-5f
#define FLT_BIG 3.402823466e+38f

static __device__ __forceinline__ ushort f2bf(float f) {
    uint u = __float_as_uint(f);
    u += 0x7FFFu + ((u >> 16) & 1u);
    return (ushort)(u >> 16);
}
static __device__ __forceinline__ float bf2f(ushort h) {
    return __uint_as_float(((uint)h) << 16);
}
union UCast { uint4 u; short8 s; };
static __device__ __forceinline__ short8 as_s8(uint4 v) { UCast c; c.u = v; return c.s; }

// ---------------- P0: sume2[h][k] = sum_c emb[k][c]^2 (exact fp32) ----------------
__global__ __launch_bounds__(256) void vq_sume2(const float* __restrict__ emb1,
                                                const float* __restrict__ emb2,
                                                float* __restrict__ sume2) {
    int r = blockIdx.x * 256 + threadIdx.x;
    const float* e = (r >> 9) ? emb2 : emb1;
    const float* row = e + (size_t)(r & 511) * SUBD;
    float s = 0.f;
#pragma unroll 8
    for (int i = 0; i < 64; ++i) {
        float4 v = *reinterpret_cast<const float4*>(row + i * 4);
        s += v.x * v.x + v.y * v.y + v.z * v.z + v.w * v.w;
    }
    sume2[r] = s;
}

// ---------------- P1: emb -> split-bf16, pre-swizzled staged layout ----------------
// embst[h][s=kh*8+cs][spl][k 0..255][pg 0..3]; phys pg holds logical group pg^((k>>1)&3)
__global__ __launch_bounds__(256) void vq_embcvt(const float* __restrict__ emb1,
                                                 const float* __restrict__ emb2,
                                                 uint4* __restrict__ embst) {
    int id = blockIdx.x * 256 + threadIdx.x;      // 0..65535
    int h   = id >> 15;
    int s   = (id >> 11) & 15;
    int spl = (id >> 10) & 1;
    int k   = (id >> 2) & 255;
    int gp  = id & 3;
    int kh = s >> 3, cs = s & 7;
    int gl = gp ^ ((k >> 1) & 3);                 // un-swizzle to logical c-group
    const float* e = h ? emb2 : emb1;
    const float* src = e + (size_t)(kh * 256 + k) * SUBD + cs * 32 + gl * 8;
    float4 v0 = *reinterpret_cast<const float4*>(src);
    float4 v1 = *reinterpret_cast<const float4*>(src + 4);
    float f[8] = {v0.x, v0.y, v0.z, v0.w, v1.x, v1.y, v1.z, v1.w};
    ushort o[8];
#pragma unroll
    for (int i = 0; i < 8; ++i) {
        ushort hh = f2bf(f[i]);
        o[i] = spl ? f2bf(f[i] - bf2f(hh)) : hh;
    }
    uint4 d;
    d.x = o[0] | ((uint)o[1] << 16);
    d.y = o[2] | ((uint)o[3] << 16);
    d.z = o[4] | ((uint)o[5] << 16);
    d.w = o[6] | ((uint)o[7] << 16);
    embst[id] = d;
}

// ---------------- A: fused convert + argmin + plane dump (1wr x 8wk) ----------------
// grid 2048 = (rblk,h); 512 thr = 8 waves; wave tile 64r x 64k, ONE k-pass.
// B fragments loaded once per block (no wr duplication) -> half the L2 traffic.
__global__ __launch_bounds__(512, 2) void vq_argmin7(const float* __restrict__ x,
                                                     const uint4* __restrict__ embst,
                                                     const float* __restrict__ sume2,
                                                     float* __restrict__ counts,
                                                     int* __restrict__ idx_out,
                                                     uint4* __restrict__ planeH,
                                                     uint4* __restrict__ planeL) {
    __shared__ uint4 Ah[2048];        // 32 KB
    __shared__ uint4 Al[2048];        // 32 KB
    __shared__ float f2p[512];
    __shared__ float f2s[64];
    __shared__ float se_l[512];
    __shared__ float wbd[8][64];
    __shared__ int   wbk[8][64];

    const int tid = threadIdx.x;
    const int h  = blockIdx.x & 1;
    const int rb = blockIdx.x >> 1;
    const int b  = rb >> 5;
    const int t0 = (rb & 31) << 6;
    const int wv = tid >> 6;
    const int lane = tid & 63;

    se_l[tid] = sume2[h * NK + tid];

    // ---- phase 1: transpose/convert x -> LDS planes (+f2 partials) ----
    {
        const int r  = lane;
        const int co = wv * 32;
        const float* xb = x + ((size_t)b * BD + h * 256 + co) * TT + t0 + r;
        float f2 = 0.f;
#pragma unroll
        for (int j4 = 0; j4 < 4; ++j4) {
            float v[8];
#pragma unroll
            for (int j = 0; j < 8; ++j) v[j] = xb[(size_t)(j4 * 8 + j) * TT];
            ushort hi[8], lo[8];
#pragma unroll
            for (int j = 0; j < 8; ++j) {
                hi[j] = f2bf(v[j]);
                lo[j] = f2bf(v[j] - bf2f(hi[j]));
                f2 += v[j] * v[j];
            }
            uint4 uh, ul;
            uh.x = hi[0] | ((uint)hi[1] << 16); uh.y = hi[2] | ((uint)hi[3] << 16);
            uh.z = hi[4] | ((uint)hi[5] << 16); uh.w = hi[6] | ((uint)hi[7] << 16);
            ul.x = lo[0] | ((uint)lo[1] << 16); ul.y = lo[2] | ((uint)lo[3] << 16);
            ul.z = lo[4] | ((uint)lo[5] << 16); ul.w = lo[6] | ((uint)lo[7] << 16);
            const int chunk = (co >> 3) + j4;
            const int phys = chunk ^ (r & 7);
            Ah[r * 32 + phys] = uh;
            Al[r * 32 + phys] = ul;
        }
        f2p[tid] = f2;
    }
    __syncthreads();

    // ---- deterministic f2 reduce + coalesced plane write-out (for vq_dwseg2) ----
    if (tid < 64) {
        float s = 0.f;
#pragma unroll
        for (int g = 0; g < 8; ++g) s += f2p[g * 64 + tid];   // ascending c order
        f2s[tid] = s;
    }
    {
        const size_t pb = (size_t)(h * 1024 + rb) * 2048;
#pragma unroll
        for (int i = 0; i < 4; ++i) {
            planeH[pb + tid + i * 512] = Ah[tid + i * 512];
            planeL[pb + tid + i * 512] = Al[tid + i * 512];
        }
    }
    __syncthreads();

    // ---- phase 2: barrier-free MFMA loop, wave owns 64 rows x 64 k ----
    const int l15 = lane & 15, l4 = lane >> 4;
    const int kh = wv >> 2;                       // wave's k-half
    const uint4* eb = embst + (size_t)h * 32768 + (size_t)(kh * 8) * 2048;
    const int bLane = (wv & 3) * 256 + l15 * 4 + (l4 ^ ((l15 >> 1) & 3));
    const int aBase = (l15 & 7);                  // row&7 is rg-invariant

    f32x4 acc[4][4];
#pragma unroll
    for (int rg = 0; rg < 4; ++rg)
#pragma unroll
        for (int kg = 0; kg < 4; ++kg) acc[rg][kg] = (f32x4)0.f;

#pragma unroll 1
    for (int cs = 0; cs < 8; ++cs) {
        uint4 bh[4], bl[4];
#pragma unroll
        for (int kg = 0; kg < 4; ++kg)
            bh[kg] = eb[(size_t)cs * 2048 + bLane + kg * 64];
#pragma unroll
        for (int kg = 0; kg < 4; ++kg)
            bl[kg] = eb[(size_t)cs * 2048 + 1024 + bLane + kg * 64];
        const int ioff = (cs * 4 + l4) ^ aBase;
        // ---- rg pair {0,1} ----
        {
            const short8 ah0 = as_s8(Ah[(l15) * 32 + ioff]);
            const short8 al0 = as_s8(Al[(l15) * 32 + ioff]);
            const short8 ah1 = as_s8(Ah[(16 + l15) * 32 + ioff]);
            const short8 al1 = as_s8(Al[(16 + l15) * 32 + ioff]);
#pragma unroll
            for (int kg = 0; kg < 4; ++kg) {
                acc[0][kg] = __builtin_amdgcn_mfma_f32_16x16x32_bf16(ah0, as_s8(bh[kg]), acc[0][kg], 0, 0, 0);
                acc[1][kg] = __builtin_amdgcn_mfma_f32_16x16x32_bf16(ah1, as_s8(bh[kg]), acc[1][kg], 0, 0, 0);
            }
#pragma unroll
            for (int kg = 0; kg < 4; ++kg) {
                acc[0][kg] = __builtin_amdgcn_mfma_f32_16x16x32_bf16(ah0, as_s8(bl[kg]), acc[0][kg], 0, 0, 0);
                acc[1][kg] = __builtin_amdgcn_mfma_f32_16x16x32_bf16(ah1, as_s8(bl[kg]), acc[1][kg], 0, 0, 0);
            }
#pragma unroll
            for (int kg = 0; kg < 4; ++kg) {
                acc[0][kg] = __builtin_amdgcn_mfma_f32_16x16x32_bf16(al0, as_s8(bh[kg]), acc[0][kg], 0, 0, 0);
                acc[1][kg] = __builtin_amdgcn_mfma_f32_16x16x32_bf16(al1, as_s8(bh[kg]), acc[1][kg], 0, 0, 0);
            }
        }
        // ---- rg pair {2,3} ----
        {
            const short8 ah2 = as_s8(Ah[(32 + l15) * 32 + ioff]);
            const short8 al2 = as_s8(Al[(32 + l15) * 32 + ioff]);
            const short8 ah3 = as_s8(Ah[(48 + l15) * 32 + ioff]);
            const short8 al3 = as_s8(Al[(48 + l15) * 32 + ioff]);
#pragma unroll
            for (int kg = 0; kg < 4; ++kg) {
                acc[2][kg] = __builtin_amdgcn_mfma_f32_16x16x32_bf16(ah2, as_s8(bh[kg]), acc[2][kg], 0, 0, 0);
                acc[3][kg] = __builtin_amdgcn_mfma_f32_16x16x32_bf16(ah3, as_s8(bh[kg]), acc[3][kg], 0, 0, 0);
            }
#pragma unroll
            for (int kg = 0; kg < 4; ++kg) {
                acc[2][kg] = __builtin_amdgcn_mfma_f32_16x16x32_bf16(ah2, as_s8(bl[kg]), acc[2][kg], 0, 0, 0);
                acc[3][kg] = __builtin_amdgcn_mfma_f32_16x16x32_bf16(ah3, as_s8(bl[kg]), acc[3][kg], 0, 0, 0);
            }
#pragma unroll
            for (int kg = 0; kg < 4; ++kg) {
                acc[2][kg] = __builtin_amdgcn_mfma_f32_16x16x32_bf16(al2, as_s8(bh[kg]), acc[2][kg], 0, 0, 0);
                acc[3][kg] = __builtin_amdgcn_mfma_f32_16x16x32_bf16(al3, as_s8(bh[kg]), acc[3][kg], 0, 0, 0);
            }
        }
    }

    // ---- argmin epilogue: per-rg lane-local + l15-shuffle reduce ----
#pragma unroll
    for (int rg = 0; rg < 4; ++rg) {
        float bd[4]; int bk[4];
#pragma unroll
        for (int reg = 0; reg < 4; ++reg) { bd[reg] = FLT_BIG; bk[reg] = 0; }
#pragma unroll
        for (int kg = 0; kg < 4; ++kg) {              // k ascending -> min-k ties
            const int k = wv * 64 + kg * 16 + l15;
            const float se = se_l[k];
#pragma unroll
            for (int reg = 0; reg < 4; ++reg) {
                const int row = rg * 16 + l4 * 4 + reg;
                const float d = (f2s[row] + se) - 2.0f * acc[rg][kg][reg];
                if (d < bd[reg]) { bd[reg] = d; bk[reg] = k; }
            }
        }
#pragma unroll
        for (int m = 1; m < 16; m <<= 1) {
#pragma unroll
            for (int reg = 0; reg < 4; ++reg) {
                const float od = __shfl_xor(bd[reg], m);
                const int   ok = __shfl_xor(bk[reg], m);
                if (od < bd[reg] || (od == bd[reg] && ok < bk[reg])) { bd[reg] = od; bk[reg] = ok; }
            }
        }
        if (l15 == 0) {
#pragma unroll
            for (int reg = 0; reg < 4; ++reg) {
                const int rr = rg * 16 + l4 * 4 + reg;
                wbd[wv][rr] = bd[reg]; wbk[wv][rr] = bk[reg];
            }
        }
    }
    __syncthreads();
    if (tid < 64) {
        float bd = wbd[0][tid]; int bk = wbk[0][tid];
#pragma unroll
        for (int q = 1; q < 8; ++q) {                 // ascending k blocks
            const float od = wbd[q][tid]; const int ok = wbk[q][tid];
            if (od < bd || (od == bd && ok < bk)) { bd = od; bk = ok; }
        }
        idx_out[h * NROWS + rb * 64 + tid] = bk;
        atomicAdd(&counts[(h << 9) + bk], 1.0f);
    }
}

// ---------------- B: cluster-major segmented sum from planes -> new_emb ------------
__global__ __launch_bounds__(256) void vq_dwseg2(const uint4* __restrict__ planeH,
                                                 const uint4* __restrict__ planeL,
                                                 const int* __restrict__ idx,
                                                 const float* __restrict__ w1,
                                                 const float* __restrict__ w2,
                                                 const float* __restrict__ csf,
                                                 float* __restrict__ nemb) {
    __shared__ ushort rows_l[4][1024];
    __shared__ int cnt_w[4];
    const int tid = threadIdx.x;
    const int h = blockIdx.x >> 9;
    const int k = blockIdx.x & 511;
    const int w = tid >> 6, lane = tid & 63;
    const ushort* pH = (const ushort*)planeH;
    const ushort* pL = (const ushort*)planeL;
    const int c = tid;
    const size_t hbase = (size_t)h * 1024 * 16384;    // ushorts per half
    float acc = 0.f;
    for (int win = 0; win < 4; ++win) {
        {
            const int base = win * 16384 + w * 4096;
            const int* ip = idx + h * NROWS + base;
            int cnt = 0;
            for (int stp = 0; stp < 64; ++stp) {
                const int rl = stp * 64 + lane;
                const bool mt = (ip[rl] == k);
                const unsigned long long m = __ballot(mt);
                if (mt) {
                    const int pos = cnt + __popcll(m & ((1ull << lane) - 1ull));
                    if (pos < 1024) rows_l[w][pos] = (ushort)rl;
                }
                cnt += __popcll(m);
            }
            if (lane == 0) cnt_w[w] = (cnt < 1024) ? cnt : 1024;
        }
        __syncthreads();
        for (int s = 0; s < 4; ++s) {
            const int n = cnt_w[s];
            const int rbase = win * 16384 + s * 4096;
            for (int i = 0; i < n; ++i) {
                const int r = rbase + rows_l[s][i];
                const size_t off = hbase + (size_t)(r >> 6) * 16384 + (r & 63) * 256
                                 + (((c >> 3) ^ (r & 7)) << 3) + (c & 7);
                acc += bf2f(pH[off]) + bf2f(pL[off]);
            }
        }
        __syncthreads();
    }
    const float* wsrc = h ? w2 : w1;
    nemb[((size_t)(h << 9) + k) * SUBD + c] =
        (DECAYF * wsrc[(size_t)k * SUBD + c] + OMDF * acc) / csf[(h << 9) + k];
}

// ---------------- D1: EMA cluster-size smoothing + perplexity ----------------
__global__ void vq_stats(const float* __restrict__ counts,
                         const float* __restrict__ cs_in1,
                         const float* __restrict__ cs_in2,
                         float* __restrict__ cs_final,
                         float* __restrict__ out) {
    __shared__ float red[512];
    const int k = threadIdx.x;
    float perp_tot = 0.f;
    for (int h = 0; h < 2; ++h) {
        const float* csin = h ? cs_in2 : cs_in1;
        float cnt = counts[(h << 9) + k];
        float csn = DECAYF * csin[k] + OMDF * cnt;
        red[k] = csn;
        __syncthreads();
        for (int s = 256; s > 0; s >>= 1) {
            if (k < s) red[k] += red[k + s];
            __syncthreads();
        }
        float n = red[0];
        __syncthreads();
        cs_final[(h << 9) + k] = (csn + EPSF) / (n + 512.0f * EPSF) * n;
        float p = cnt * (1.0f / 65536.0f);
        float e = p * logf(p + 1e-10f);
        red[k] = e;
        __syncthreads();
        for (int s = 256; s > 0; s >>= 1) {
            if (k < s) red[k] += red[k + s];
            __syncthreads();
        }
        if (k == 0) perp_tot += expf(-red[0]);
        __syncthreads();
    }
    if (k == 0) out[33554433] = perp_tot;
}

// ---------------- fallback chain (ws too small for planes) ----------------
__global__ __launch_bounds__(512) void vq_argmin3(const float* __restrict__ x,
                                                  const uint4* __restrict__ embst,
                                                  const float* __restrict__ sume2,
                                                  float* __restrict__ counts,
                                                  int* __restrict__ idx_out) {
    __shared__ uint4 Ah[2048];
    __shared__ uint4 Al[2048];
    __shared__ uint4 Bb[2][2048];
    __shared__ float f2s[64];
    __shared__ float se_l[512];
    __shared__ float wbd[4][64];
    __shared__ int   wbk[4][64];
    const int tid = threadIdx.x;
    const int h  = blockIdx.x & 1;
    const int rb = blockIdx.x >> 1;
    const int b  = rb >> 5;
    const int t0 = (rb & 31) << 6;
    if (tid < 64) f2s[tid] = 0.f;
    se_l[tid] = sume2[h * NK + tid];
    __syncthreads();
    {
        const int r  = tid & 63;
        const int cq = tid >> 6;
        const float* xb = x + ((size_t)b * BD + h * 256) * TT + t0 + r;
        float f2p = 0.f;
#pragma unroll
        for (int it = 0; it < 4; ++it) {
            const int c0 = cq * 32 + it * 8;
            float v[8];
#pragma unroll
            for (int j = 0; j < 8; ++j) v[j] = xb[(size_t)(c0 + j) * TT];
            ushort hi[8], lo[8];
#pragma unroll
            for (int j = 0; j < 8; ++j) {
                hi[j] = f2bf(v[j]);
                lo[j] = f2bf(v[j] - bf2f(hi[j]));
                f2p += v[j] * v[j];
            }
            uint4 uh, ul;
            uh.x = hi[0] | ((uint)hi[1] << 16); uh.y = hi[2] | ((uint)hi[3] << 16);
            uh.z = hi[4] | ((uint)hi[5] << 16); uh.w = hi[6] | ((uint)hi[7] << 16);
            ul.x = lo[0] | ((uint)lo[1] << 16); ul.y = lo[2] | ((uint)lo[3] << 16);
            ul.z = lo[4] | ((uint)lo[5] << 16); ul.w = lo[6] | ((uint)lo[7] << 16);
            const int phys = (c0 >> 3) ^ (r & 7);
            Ah[r * 32 + phys] = uh;
            Al[r * 32 + phys] = ul;
        }
        atomicAdd(&f2s[r], f2p);
    }
    {
        const uint4* src = embst + (size_t)h * 32768;
#pragma unroll
        for (int i = 0; i < 4; ++i) Bb[0][tid + i * 512] = src[tid + i * 512];
    }
    __syncthreads();
    const int l = tid & 63;
    const int wv = tid >> 6;
    const int wr = wv >> 2, wk = wv & 3;
    const int l15 = l & 15, l4 = l >> 4;
    const int bBase = l15 * 4 + (l4 ^ ((l15 >> 1) & 3));
    float bd8[8]; int bk8[8];
#pragma unroll
    for (int i = 0; i < 8; ++i) { bd8[i] = FLT_BIG; bk8[i] = 0; }
    int buf = 0;
    for (int kh = 0; kh < 2; ++kh) {
        f32x4 acc[2][4];
#pragma unroll
        for (int rg = 0; rg < 2; ++rg)
#pragma unroll
            for (int kg = 0; kg < 4; ++kg) acc[rg][kg] = (f32x4)0.f;
        for (int cs = 0; cs < 8; ++cs) {
            const int s = kh * 8 + cs;
            uint4 st[4];
            const bool pf = (s < 15);
            if (pf) {
                const uint4* src = embst + (size_t)h * 32768 + (size_t)(s + 1) * 2048;
#pragma unroll
                for (int i = 0; i < 4; ++i) st[i] = src[tid + i * 512];
            }
            short8 ah[2], al[2];
#pragma unroll
            for (int rg = 0; rg < 2; ++rg) {
                const int row = wr * 32 + rg * 16 + l15;
                const int ia = row * 32 + ((cs * 4 + l4) ^ (row & 7));
                ah[rg] = as_s8(Ah[ia]);
                al[rg] = as_s8(Al[ia]);
            }
            short8 bh[4], bl[4];
#pragma unroll
            for (int kg = 0; kg < 4; ++kg) {
                const int ib = wk * 256 + kg * 64 + bBase;
                bh[kg] = as_s8(Bb[buf][ib]);
                bl[kg] = as_s8(Bb[buf][1024 + ib]);
            }
#pragma unroll
            for (int rg = 0; rg < 2; ++rg)
#pragma unroll
                for (int kg = 0; kg < 4; ++kg) {
                    acc[rg][kg] = __builtin_amdgcn_mfma_f32_16x16x32_bf16(ah[rg], bh[kg], acc[rg][kg], 0, 0, 0);
                    acc[rg][kg] = __builtin_amdgcn_mfma_f32_16x16x32_bf16(ah[rg], bl[kg], acc[rg][kg], 0, 0, 0);
                    acc[rg][kg] = __builtin_amdgcn_mfma_f32_16x16x32_bf16(al[rg], bh[kg], acc[rg][kg], 0, 0, 0);
                }
            if (pf) {
#pragma unroll
                for (int i = 0; i < 4; ++i) Bb[buf ^ 1][tid + i * 512] = st[i];
            }
            __syncthreads();
            buf ^= 1;
        }
#pragma unroll
        for (int rg = 0; rg < 2; ++rg)
#pragma unroll
            for (int kg = 0; kg < 4; ++kg) {
                const int k = kh * 256 + wk * 64 + kg * 16 + l15;
                const float se = se_l[k];
#pragma unroll
                for (int reg = 0; reg < 4; ++reg) {
                    const int row = wr * 32 + rg * 16 + l4 * 4 + reg;
                    const float d = (f2s[row] + se) - 2.0f * acc[rg][kg][reg];
                    const int i8 = rg * 4 + reg;
                    if (d < bd8[i8]) { bd8[i8] = d; bk8[i8] = k; }
                }
            }
    }
#pragma unroll
    for (int m = 1; m < 16; m <<= 1) {
#pragma unroll
        for (int i = 0; i < 8; ++i) {
            const float od = __shfl_xor(bd8[i], m);
            const int   ok = __shfl_xor(bk8[i], m);
            if (od < bd8[i] || (od == bd8[i] && ok < bk8[i])) { bd8[i] = od; bk8[i] = ok; }
        }
    }
    if (l15 == 0) {
#pragma unroll
        for (int i = 0; i < 8; ++i) {
            const int rg = i >> 2, reg = i & 3;
            const int rr = wr * 32 + rg * 16 + l4 * 4 + reg;
            wbd[wk][rr] = bd8[i]; wbk[wk][rr] = bk8[i];
        }
    }
    __syncthreads();
    if (tid < 64) {
        float bd = wbd[0][tid]; int bk = wbk[0][tid];
#pragma unroll
        for (int q = 1; q < 4; ++q) {
            const float od = wbd[q][tid]; const int ok = wbk[q][tid];
            if (od < bd || (od == bd && ok < bk)) { bd = od; bk = ok; }
        }
        idx_out[h * NROWS + b * TT + t0 + tid] = bk;
        atomicAdd(&counts[(h << 9) + bk], 1.0f);
    }
}

__global__ __launch_bounds__(256) void vq_dw(const float* __restrict__ x,
                                             const int* __restrict__ idx,
                                             float* __restrict__ dw) {
    __shared__ float dwp[64 * 512];
    const int tid = threadIdx.x;
    const int h = blockIdx.x & 1;
    const int cr = (blockIdx.x >> 1) & 3;
    const int slab = blockIdx.x >> 3;
#pragma unroll 8
    for (int i = 0; i < 128; ++i) dwp[tid + i * 256] = 0.f;
    __syncthreads();
    for (int it = 0; it < 16; ++it) {
        const int r = (slab << 12) + (it << 8) + tid;
        const int k = idx[(h << 16) + r];
        const float* xb = x + ((size_t)(r >> 11) * BD + (h << 8) + (cr << 6)) * TT + (r & 2047);
#pragma unroll
        for (int c = 0; c < 64; ++c)
            atomicAdd(&dwp[(c << 9) + k], xb[(size_t)c * TT]);
    }
    __syncthreads();
#pragma unroll 8
    for (int i = 0; i < 128; ++i) {
        const int j = tid + i * 256;
        atomicAdd(&dw[(size_t)((h << 9) + (j & 511)) * SUBD + (cr << 6) + (j >> 9)], dwp[j]);
    }
}

__global__ __launch_bounds__(256) void vq_newemb(const float* __restrict__ dw,
                                                 const float* __restrict__ w1,
                                                 const float* __restrict__ w2,
                                                 const float* __restrict__ cs_final,
                                                 float* __restrict__ new_emb) {
    int g = blockIdx.x * 256 + threadIdx.x;
    int h = g >> 15;
    int k = (g >> 6) & 511;
    const float* wi = h ? w2 : w1;
    float4 d4 = *reinterpret_cast<const float4*>(dw + (size_t)g * 4);
    float4 w4 = *reinterpret_cast<const float4*>(wi + (size_t)(g & 32767) * 4);
    float cs = cs_final[(h << 9) + k];
    float4 o;
    o.x = (DECAYF * w4.x + OMDF * d4.x) / cs;
    o.y = (DECAYF * w4.y + OMDF * d4.y) / cs;
    o.z = (DECAYF * w4.z + OMDF * d4.z) / cs;
    o.w = (DECAYF * w4.w + OMDF * d4.w) / cs;
    *reinterpret_cast<float4*>(new_emb + (size_t)g * 4) = o;
}

// ---------------- E: gather + output + vq_loss (split per half, more TLP) ----------
__global__ __launch_bounds__(256) void vq_out2(const float* __restrict__ x,
                                               const float* __restrict__ nemb,
                                               const int* __restrict__ idx,
                                               float* __restrict__ out) {
    __shared__ int idx_l[64];
    __shared__ float wsum[4];
    const int tid = threadIdx.x;
    const int h  = blockIdx.x & 1;
    const int rb = blockIdx.x >> 1;
    const int b  = rb >> 5;
    const int t0 = (rb & 31) << 6;
    if (tid < 64) idx_l[tid] = idx[h * NROWS + b * TT + t0 + tid];
    __syncthreads();
    const int tq = tid & 15;
    const int cw = tid >> 4;
    const int k0 = idx_l[tq * 4 + 0], k1 = idx_l[tq * 4 + 1];
    const int k2 = idx_l[tq * 4 + 2], k3 = idx_l[tq * 4 + 3];
    const float* nb = nemb + (size_t)(h << 9) * SUBD;
    float lsum = 0.f;
#pragma unroll 4
    for (int i = 0; i < 16; ++i) {
        const int c = cw + i * 16;
        const size_t base = ((size_t)b * BD + h * 256 + c) * TT + t0 + tq * 4;
        float4 xv = *reinterpret_cast<const float4*>(x + base);
        float q0 = nb[(size_t)k0 * SUBD + c];
        float q1 = nb[(size_t)k1 * SUBD + c];
        float q2 = nb[(size_t)k2 * SUBD + c];
        float q3 = nb[(size_t)k3 * SUBD + c];
        float4 o; float t1;
        t1 = q0 - xv.x; o.x = xv.x + t1; lsum += t1 * t1;
        t1 = q1 - xv.y; o.y = xv.y + t1; lsum += t1 * t1;
        t1 = q2 - xv.z; o.z = xv.z + t1; lsum += t1 * t1;
        t1 = q3 - xv.w; o.w = xv.w + t1; lsum += t1 * t1;
        *reinterpret_cast<float4*>(out + base) = o;
    }
#pragma unroll
    for (int m = 1; m < 64; m <<= 1) lsum += __shfl_xor(lsum, m);
    if ((tid & 63) == 0) wsum[tid >> 6] = lsum;
    __syncthreads();
    if (tid == 0) {
        float s = wsum[0] + wsum[1] + wsum[2] + wsum[3];
        atomicAdd(out + 33554432, s * (0.25f / 33554432.0f));
    }
}

extern "C" void kernel_launch(void* const* d_in, const int* in_sizes, int n_in,
                              void* d_out, int out_size, void* d_ws, size_t ws_size,
                              hipStream_t stream) {
    const float* x    = (const float*)d_in[0];
    const float* emb1 = (const float*)d_in[1];
    const float* emb2 = (const float*)d_in[2];
    const float* cs1  = (const float*)d_in[3];
    const float* w1   = (const float*)d_in[4];
    const float* cs2  = (const float*)d_in[5];
    const float* w2   = (const float*)d_in[6];
    float* out = (float*)d_out;
    float* ws  = (float*)d_ws;

    float* counts = ws;                     // 1024
    float* csf    = ws + 1024;              // 1024
    float* se2    = ws + 2048;              // 1024
    float* nemb   = ws + 3072;              // 262144
    int*   idx    = (int*)(ws + 265216);    // 131072 ints
    uint4* embst  = (uint4*)(ws + 396288);  // 65536 uint4 (1 MB)
    uint4* planeH = (uint4*)(ws + 789504);  // 4M uint4 (64 MB)
    uint4* planeL = (uint4*)(ws + 17566720);// 4M uint4 (64 MB)
    float* dw     = ws + 789504;            // fallback only (overlaps planeH)

    const size_t NEED = (size_t)(789504 + 2 * 16777216) * 4;
    const bool fast = (ws_size >= NEED);

    hipMemsetAsync(counts, 0, 1024 * sizeof(float), stream);
    hipMemsetAsync(out + 33554432, 0, 2 * sizeof(float), stream);

    vq_sume2 <<<4,   256, 0, stream>>>(emb1, emb2, se2);
    vq_embcvt<<<256, 256, 0, stream>>>(emb1, emb2, embst);

    if (fast) {
        vq_argmin7<<<2048, 512, 0, stream>>>(x, embst, se2, counts, idx, planeH, planeL);
        vq_stats  <<<1,    512, 0, stream>>>(counts, cs1, cs2, csf, out);
        vq_dwseg2 <<<1024, 256, 0, stream>>>(planeH, planeL, idx, w1, w2, csf, nemb);
    } else {
        hipMemsetAsync(dw, 0, 262144 * sizeof(float), stream);
        vq_argmin3<<<2048, 512, 0, stream>>>(x, embst, se2, counts, idx);
        vq_dw     <<<128,  256, 0, stream>>>(x, idx, dw);
        vq_stats  <<<1,    512, 0, stream>>>(counts, cs1, cs2, csf, out);
        vq_newemb <<<256,  256, 0, stream>>>(dw, w1, w2, csf, nemb);
    }
    vq_out2<<<2048, 256, 0, stream>>>(x, nemb, idx, out);
}